// Round 5
// baseline (767.864 us; speedup 1.0000x reference)
//
#include <hip/hip_runtime.h>
#include <math.h>
#include <type_traits>

#define NN 50000
#define EE 800000
#define IN_D 256
#define HH 128
#define OUT_D 64
#define DEPTH 3

typedef unsigned short u16;
typedef __bf16  bf16x8 __attribute__((ext_vector_type(8)));
typedef short   short8 __attribute__((ext_vector_type(8)));
typedef float   f32x4  __attribute__((ext_vector_type(4)));

__device__ __forceinline__ u16 f2b(float f){
    unsigned u = __float_as_uint(f);
    u += 0x7fff + ((u>>16)&1);            // round-to-nearest-even
    return (u16)(u>>16);
}
__device__ __forceinline__ float b2f(u16 h){ return __uint_as_float(((unsigned)h)<<16); }
__device__ __forceinline__ float sigm(float x){ return 1.f/(1.f+expf(-x)); }

__device__ __forceinline__ bf16x8 lda_bf(const u16* p){  // 16B global load as bf16x8
    return *(const bf16x8*)p;
}
__device__ __forceinline__ bf16x8 lda_f32(const float* p){ // 8 f32 -> bf16x8
    float4 x0 = *(const float4*)p;
    float4 x1 = *(const float4*)(p+4);
    short8 v;
    v[0]=(short)f2b(x0.x); v[1]=(short)f2b(x0.y); v[2]=(short)f2b(x0.z); v[3]=(short)f2b(x0.w);
    v[4]=(short)f2b(x1.x); v[5]=(short)f2b(x1.y); v[6]=(short)f2b(x1.z); v[7]=(short)f2b(x1.w);
    return __builtin_bit_cast(bf16x8, v);
}

// ---------------- register-direct MFMA GEMM (no LDS, no barriers) ----------------
// Block = 64 rows x MT*32 cols, 4 waves (2 row x 2 col). Fragments straight from
// global: per-lane 16B, 16 rows/frag = 16 full 64B lines; B is L2-resident.
enum { EPI_BF=0, EPI_RELU=1 };

template<int EPI, int MT, typename TA>
__global__ __launch_bounds__(256) void mgemm_k(
    const TA* __restrict__ A1, int K,
    const u16* __restrict__ Bt, const float* __restrict__ bias,
    void* __restrict__ Out, int Nrows)
{
    constexpr int M = MT*32;
    const int tid  = threadIdx.x;
    const int lane = tid & 63;
    const int w    = tid >> 6;
    const int wrow = (w>>1)*32, wcol = (w&1)*(MT*16);
    const int rb   = blockIdx.x*64;
    const int ml = lane & 15, kh = (lane>>4)*8;
    f32x4 acc[2][MT] = {};
    int r0 = rb + wrow + ml;      if (r0 >= Nrows) r0 = Nrows-1;
    int r1 = rb + wrow + 16 + ml; if (r1 >= Nrows) r1 = Nrows-1;

    for (int k0 = 0; k0 < K; k0 += 32) {
        bf16x8 a0, a1;
        if constexpr (std::is_same<TA,float>::value) {
            a0 = lda_f32(A1 + (size_t)r0*K + k0 + kh);
            a1 = lda_f32(A1 + (size_t)r1*K + k0 + kh);
        } else {
            a0 = lda_bf(A1 + (size_t)r0*K + k0 + kh);
            a1 = lda_bf(A1 + (size_t)r1*K + k0 + kh);
        }
        #pragma unroll
        for (int j = 0; j < MT; ++j) {
            bf16x8 bf = lda_bf(Bt + (size_t)(wcol + j*16 + ml)*K + k0 + kh);
            acc[0][j] = __builtin_amdgcn_mfma_f32_16x16x32_bf16(a0, bf, acc[0][j], 0,0,0);
            acc[1][j] = __builtin_amdgcn_mfma_f32_16x16x32_bf16(a1, bf, acc[1][j], 0,0,0);
        }
    }
    const int rq = (lane>>4)*4;
    #pragma unroll
    for (int i = 0; i < 2; ++i)
    #pragma unroll
    for (int r = 0; r < 4; ++r) {
        int row = rb + wrow + i*16 + rq + r;
        if (row >= Nrows) continue;
        #pragma unroll
        for (int j = 0; j < MT; ++j) {
            int gc = wcol + j*16 + ml;
            float vv = acc[i][j][r];
            if (bias) vv += bias[gc];
            size_t o = (size_t)row*M + gc;
            if (EPI==EPI_BF)   ((u16*)Out)[o]   = f2b(vv);
            if (EPI==EPI_RELU) ((float*)Out)[o] = fmaxf(vv, 0.f);
        }
    }
}

// ---------------- z-GEMM with fused el/er epilogue (no LDS in k-loop) ----------------
__global__ __launch_bounds__(256) void zel_k(
    const u16* __restrict__ A1,
    const u16* __restrict__ Bt, const float* __restrict__ al, const float* __restrict__ ar,
    u16* __restrict__ Out, float* __restrict__ el, float* __restrict__ er, int Nrows)
{
    __shared__ float elp[64][2], erp[64][2];
    const int tid  = threadIdx.x;
    const int lane = tid & 63;
    const int w    = tid >> 6;
    const int wrow = (w>>1)*32, wcol = (w&1)*64;
    const int rb   = blockIdx.x*64;
    const int ml = lane & 15, kh = (lane>>4)*8;
    f32x4 acc[2][4] = {};
    int r0 = rb + wrow + ml;      if (r0 >= Nrows) r0 = Nrows-1;
    int r1 = rb + wrow + 16 + ml; if (r1 >= Nrows) r1 = Nrows-1;

    for (int k0 = 0; k0 < HH; k0 += 32) {
        bf16x8 a0 = lda_bf(A1 + (size_t)r0*HH + k0 + kh);
        bf16x8 a1 = lda_bf(A1 + (size_t)r1*HH + k0 + kh);
        #pragma unroll
        for (int j = 0; j < 4; ++j) {
            bf16x8 bf = lda_bf(Bt + (size_t)(wcol + j*16 + ml)*HH + k0 + kh);
            acc[0][j] = __builtin_amdgcn_mfma_f32_16x16x32_bf16(a0, bf, acc[0][j], 0,0,0);
            acc[1][j] = __builtin_amdgcn_mfma_f32_16x16x32_bf16(a1, bf, acc[1][j], 0,0,0);
        }
    }
    const int rq = (lane>>4)*4;
    float pel[2][4] = {}, per2[2][4] = {};
    #pragma unroll
    for (int j = 0; j < 4; ++j) {
        int gc = wcol + j*16 + ml;
        float alc = al[gc], arc = ar[gc];
        #pragma unroll
        for (int i = 0; i < 2; ++i)
        #pragma unroll
        for (int r = 0; r < 4; ++r) {
            int row = rb + wrow + i*16 + rq + r;
            float vv = acc[i][j][r];
            if (row < Nrows) Out[(size_t)row*HH + gc] = f2b(vv);
            pel[i][r]  = fmaf(vv, alc, pel[i][r]);
            per2[i][r] = fmaf(vv, arc, per2[i][r]);
        }
    }
    #pragma unroll
    for (int msk = 1; msk < 16; msk <<= 1)
        #pragma unroll
        for (int i = 0; i < 2; ++i)
        #pragma unroll
        for (int r = 0; r < 4; ++r) {
            pel[i][r]  += __shfl_xor(pel[i][r],  msk);
            per2[i][r] += __shfl_xor(per2[i][r], msk);
        }
    if (ml == 0) {
        #pragma unroll
        for (int i = 0; i < 2; ++i)
        #pragma unroll
        for (int r = 0; r < 4; ++r) {
            int lr = wrow + i*16 + rq + r;
            elp[lr][w&1] = pel[i][r];
            erp[lr][w&1] = per2[i][r];
        }
    }
    __syncthreads();
    if (tid < 64) {
        int row = rb + tid;
        if (row < Nrows) {
            el[row] = elp[tid][0] + elp[tid][1];
            er[row] = erp[tid][0] + erp[tid][1];
        }
    }
}

// ---------------- fused 4-gate GEMM + c/mu update (no LDS, no barriers) ----------------
// Bt4: [512][256] = [ig|st|fg|og] rows, K=256.  A = concat(coll, mu).
// In-place mu safe: block reads only its own 64 rows in k-loop, writes them in epilogue.
template<bool FIRST>
__global__ __launch_bounds__(256) void gates_k(
    const u16* __restrict__ A1, const u16* __restrict__ A2,
    const u16* __restrict__ Bt4,
    const float* __restrict__ igb, const float* __restrict__ stb,
    const float* __restrict__ fgb, const float* __restrict__ ogb,
    float* __restrict__ cbuf, u16* __restrict__ mu, int Nrows)
{
    const int tid  = threadIdx.x;
    const int lane = tid & 63;
    const int w    = tid >> 6;
    const int wrow = (w>>1)*32, wcol = (w&1)*64;
    const int rb   = blockIdx.x*64;
    const int ml = lane & 15, kh = (lane>>4)*8;
    f32x4 acc[2][4][4] = {};   // [rowtile][gate][coltile]
    int r0 = rb + wrow + ml;      if (r0 >= Nrows) r0 = Nrows-1;
    int r1 = rb + wrow + 16 + ml; if (r1 >= Nrows) r1 = Nrows-1;

    for (int k0 = 0; k0 < 2*HH; k0 += 32) {
        const u16* Ap = (k0 < HH) ? A1 : A2;
        int kk = k0 & (HH-1);
        bf16x8 a0 = lda_bf(Ap + (size_t)r0*HH + kk + kh);
        bf16x8 a1 = lda_bf(Ap + (size_t)r1*HH + kk + kh);
        #pragma unroll
        for (int g = 0; g < 4; ++g)
        #pragma unroll
        for (int j = 0; j < 4; ++j) {
            bf16x8 bf = lda_bf(Bt4 + (size_t)(g*128 + wcol + j*16 + ml)*(2*HH) + k0 + kh);
            acc[0][g][j] = __builtin_amdgcn_mfma_f32_16x16x32_bf16(a0, bf, acc[0][g][j], 0,0,0);
            acc[1][g][j] = __builtin_amdgcn_mfma_f32_16x16x32_bf16(a1, bf, acc[1][g][j], 0,0,0);
        }
    }
    const int rq = (lane>>4)*4;
    #pragma unroll
    for (int i = 0; i < 2; ++i)
    #pragma unroll
    for (int r = 0; r < 4; ++r) {
        int row = rb + wrow + i*16 + rq + r;
        if (row >= Nrows) continue;
        #pragma unroll
        for (int j = 0; j < 4; ++j) {
            int gc = wcol + j*16 + ml;
            size_t o = (size_t)row*HH + gc;
            float ig = sigm (acc[i][0][j][r] + igb[gc]);
            float st = tanhf(acc[i][1][j][r] + stb[gc]);
            float fg = sigm (acc[i][2][j][r] + fgb[gc]);
            float og = sigm (acc[i][3][j][r] + ogb[gc]);
            float P  = ig * st;
            float cn = FIRST ? P : fmaf(fg, cbuf[o], P);
            cbuf[o] = cn;
            mu[o] = f2b(og * tanhf(cn));
        }
    }
}

// ---------------- weight transpose+convert: dst[m*K+k] = src[k*M+m] ----------------
struct WT  { const float* s; u16* d; int K; int M; };
struct WTs { WT t[17]; };
__global__ __launch_bounds__(256) void wtrans_k(WTs ws){
    const WT t = ws.t[blockIdx.y];
    int o = blockIdx.x*256 + threadIdx.x;
    int tot = t.K * t.M;
    if (o >= tot) return;
    int m = o / t.K, k = o - m*t.K;
    t.d[o] = f2b(t.s[(size_t)k*t.M + m]);
}

// ---------------- per-node attention: alpha[p] = softmax over incoming edges ----------------
__global__ __launch_bounds__(256) void attn_k(
    const float* __restrict__ el, const float* __restrict__ er,
    const int* __restrict__ srcs, const int* __restrict__ rp, const int* __restrict__ deg,
    float* __restrict__ alpha)
{
    int n = blockIdx.x*4 + (threadIdx.x>>6);
    if (n >= NN) return;
    int lane = threadIdx.x & 63;
    int start = rp[n], cnt = deg[n];
    float ern = er[n];
    float m = -1e30f;
    for (int i=lane; i<cnt; i+=64) {
        float v = el[srcs[start+i]] + ern;
        v = v >= 0.f ? v : 0.2f*v;
        alpha[start+i] = v;
        m = fmaxf(m, v);
    }
    #pragma unroll
    for (int off=1; off<64; off<<=1) m = fmaxf(m, __shfl_xor(m, off));
    float s = 0.f;
    for (int i=lane; i<cnt; i+=64) s += expf(alpha[start+i] - m);
    #pragma unroll
    for (int off=1; off<64; off<<=1) s += __shfl_xor(s, off);
    float inv = 1.f / fmaxf(s, 1e-16f);
    for (int i=lane; i<cnt; i+=64) alpha[start+i] = expf(alpha[start+i] - m) * inv;
}

// ---------------- per-node weighted gather: h = tanh(sum alpha * z[src] + b) ----------------
__global__ __launch_bounds__(256) void agg_k(
    const u16* __restrict__ z, const float* __restrict__ alpha,
    const int* __restrict__ srcs, const int* __restrict__ rp, const int* __restrict__ deg,
    const float* __restrict__ bias, u16* __restrict__ hout)
{
    int n = blockIdx.x*4 + (threadIdx.x>>6);
    if (n >= NN) return;
    int lane = threadIdx.x & 63;
    int start = rp[n], cnt = deg[n];
    const int slot = lane >> 4;
    const int ch   = (lane & 15) * 8;
    float acc[8] = {};
    for (int i = slot; i < cnt; i += 4) {
        int p = start + i;
        float wgt = alpha[p];
        short8 v = *(const short8*)(z + (size_t)srcs[p]*HH + ch);
        #pragma unroll
        for (int j=0;j<8;j++) acc[j] = fmaf(wgt, b2f((u16)v[j]), acc[j]);
    }
    #pragma unroll
    for (int j=0;j<8;j++){ acc[j] += __shfl_xor(acc[j],16); acc[j] += __shfl_xor(acc[j],32); }
    if (slot == 0) {
        short8 o8;
        #pragma unroll
        for (int j=0;j<8;j++) o8[j] = (short)f2b(tanhf(acc[j] + bias[ch+j]));
        *(short8*)(hout + (size_t)n*HH + ch) = o8;
    }
}

// ---------------- CSR build (by dst) ----------------
__global__ void count_k(const int* __restrict__ dst, int* __restrict__ deg){
    int e = blockIdx.x*256 + threadIdx.x;
    if (e < EE) atomicAdd(&deg[dst[e]], 1);
}
__global__ __launch_bounds__(256) void scan1_k(const int* __restrict__ deg, int* __restrict__ rp,
                                               int* __restrict__ bsum, int n){
    __shared__ int s[256];
    int t = threadIdx.x, idx = blockIdx.x*256 + t;
    int v = (idx < n) ? deg[idx] : 0;
    s[t] = v; __syncthreads();
    for (int off=1; off<256; off<<=1){ int x = (t>=off)? s[t-off] : 0; __syncthreads(); s[t] += x; __syncthreads(); }
    if (idx < n) rp[idx] = s[t] - v;
    if (t == 255) bsum[blockIdx.x] = s[255];
}
__global__ __launch_bounds__(256) void scan2_k(int* __restrict__ bsum, int nb){
    __shared__ int s[256];
    int t = threadIdx.x;
    int v = (t < nb) ? bsum[t] : 0;
    s[t] = v; __syncthreads();
    for (int off=1; off<256; off<<=1){ int x = (t>=off)? s[t-off] : 0; __syncthreads(); s[t] += x; __syncthreads(); }
    if (t < nb) bsum[t] = s[t] - v;
}
__global__ void scan3_k(int* __restrict__ rp, const int* __restrict__ bsum, int n){
    int idx = blockIdx.x*256 + threadIdx.x;
    if (idx < n) rp[idx] += bsum[blockIdx.x];
}
__global__ void fill_k(const int* __restrict__ dst, const int* __restrict__ src,
                       const int* __restrict__ rp, int* __restrict__ cursor,
                       int* __restrict__ srcs){
    int e = blockIdx.x*256 + threadIdx.x;
    if (e >= EE) return;
    int d = dst[e];
    int pos = rp[d] + atomicAdd(&cursor[d], 1);
    srcs[pos] = src[e];
}

extern "C" void kernel_launch(void* const* d_in, const int* in_sizes, int n_in,
                              void* d_out, int out_size, void* d_ws, size_t ws_size,
                              hipStream_t stream)
{
    const float* x    = (const float*)d_in[0];
    const int*   src  = (const int*)d_in[1];
    const int*   dst  = (const int*)d_in[2];
    const float* wxW  = (const float*)d_in[3];
    const float* wxb  = (const float*)d_in[4];
    const float* gatW = (const float*)d_in[5];
    const float* gatb = (const float*)d_in[6];
    const float* attl = (const float*)d_in[7];
    const float* attr = (const float*)d_in[8];
    const float* igW  = (const float*)d_in[9];
    const float* igb  = (const float*)d_in[10];
    const float* fgW  = (const float*)d_in[11];
    const float* fgb  = (const float*)d_in[12];
    const float* ogW  = (const float*)d_in[13];
    const float* ogb  = (const float*)d_in[14];
    const float* stW  = (const float*)d_in[15];
    const float* stb  = (const float*)d_in[16];
    const float* outW = (const float*)d_in[17];
    const float* outb = (const float*)d_in[18];

    char* w = (char*)d_ws;
    auto alloc = [&](size_t bytes)->char* { char* p = w; w += (bytes + 255) & ~(size_t)255; return p; };
    const size_t NH = (size_t)NN * HH;
    u16*   muB    = (u16*)alloc(NH*2);            // h0 -> mu (bf16 master)
    u16*   zB     = (u16*)alloc(NH*2);
    u16*   coll0  = (u16*)alloc(NH*2);
    u16*   coll1  = (u16*)alloc(NH*2);
    u16*   coll2  = (u16*)alloc(NH*2);
    float* cbuf   = (float*)alloc(NH*4);
    float* el     = (float*)alloc((size_t)NN*4);
    float* er     = (float*)alloc((size_t)NN*4);
    float* alpha  = (float*)alloc((size_t)EE*4);
    int*   deg    = (int*)alloc((size_t)NN*4);
    int*   cursor = (int*)alloc((size_t)NN*4);
    int*   rp     = (int*)alloc((size_t)NN*4);
    int*   bsum   = (int*)alloc(256*4);
    int*   srcs   = (int*)alloc((size_t)EE*4);
    u16*   btpool = (u16*)alloc(483328*2);
    u16* wxT   = btpool;            // [128][256]
    u16* gatT  = btpool + 32768;    // 3 x [128][128]
    u16* gate4 = btpool + 81920;    // 3 x [512][256]: [ig|st|fg|og]
    u16* outT  = btpool + 475136;   // [64][128]
    u16* coll[3] = {coll0, coll1, coll2};

    // ---- weight transposes (17 matrices, one batched launch) ----
    WTs ws_h;
    ws_h.t[0] = {wxW, wxT, IN_D, HH};
    for (int i=0;i<3;i++) ws_h.t[1+i]  = {gatW + (size_t)i*HH*HH,   gatT  + i*HH*HH,           HH,   HH};
    for (int i=0;i<3;i++) ws_h.t[4+i]  = {igW  + (size_t)i*2*HH*HH, gate4 + i*131072,          2*HH, HH};
    for (int i=0;i<3;i++) ws_h.t[7+i]  = {stW  + (size_t)i*2*HH*HH, gate4 + i*131072 + 32768,  2*HH, HH};
    for (int i=0;i<3;i++) ws_h.t[10+i] = {fgW  + (size_t)i*2*HH*HH, gate4 + i*131072 + 65536,  2*HH, HH};
    for (int i=0;i<3;i++) ws_h.t[13+i] = {ogW  + (size_t)i*2*HH*HH, gate4 + i*131072 + 98304,  2*HH, HH};
    ws_h.t[16] = {outW, outT, HH, OUT_D};
    wtrans_k<<<dim3(128,17), 256, 0, stream>>>(ws_h);

    // ---- CSR by dst ----
    hipMemsetAsync(deg, 0, (size_t)NN*4, stream);
    hipMemsetAsync(cursor, 0, (size_t)NN*4, stream);
    count_k<<<(EE+255)/256, 256, 0, stream>>>(dst, deg);
    int nb = (NN+255)/256;
    scan1_k<<<nb, 256, 0, stream>>>(deg, rp, bsum, NN);
    scan2_k<<<1, 256, 0, stream>>>(bsum, nb);
    scan3_k<<<nb, 256, 0, stream>>>(rp, bsum, NN);
    fill_k<<<(EE+255)/256, 256, 0, stream>>>(dst, src, rp, cursor, srcs);

    const int gN = (NN + 63) / 64;   // 782 blocks
    const int gA = (NN + 3) / 4;     // 12500 blocks

    // ---- h0 = x @ wxW + wxb  -> muB (bf16) ----
    mgemm_k<EPI_BF,4,float><<<gN, 256, 0, stream>>>(x, IN_D, wxT, wxb, muB, NN);

    // ---- GAT layers ----
    const u16* hin = muB;
    for (int i = 0; i < DEPTH; ++i) {
        zel_k<<<gN, 256, 0, stream>>>(hin, gatT + i*HH*HH, attl + i*HH, attr + i*HH,
                                      zB, el, er, NN);
        attn_k<<<gA, 256, 0, stream>>>(el, er, srcs, rp, deg, alpha);
        agg_k<<<gA, 256, 0, stream>>>(zB, alpha, srcs, rp, deg, gatb + i*HH, coll[i]);
        hin = coll[i];
    }

    // ---- depth (fused 4-gate per layer) ----
    gates_k<true><<<gN, 256, 0, stream>>>(coll[0], muB, gate4,
        igb, stb, fgb, ogb, cbuf, muB, NN);
    for (int i = 1; i < DEPTH; ++i)
        gates_k<false><<<gN, 256, 0, stream>>>(coll[i], muB, gate4 + i*131072,
            igb + i*HH, stb + i*HH, fgb + i*HH, ogb + i*HH, cbuf, muB, NN);

    // ---- out = relu(mu @ outW + outb) -> f32 ----
    mgemm_k<EPI_RELU,2,u16><<<gN, 256, 0, stream>>>(muB, HH, outT, outb, (float*)d_out, NN);
}

// Round 6
// 519.449 us; speedup vs baseline: 1.4782x; 1.4782x over previous
//
#include <hip/hip_runtime.h>
#include <math.h>
#include <type_traits>

#define NN 50000
#define EE 800000
#define IN_D 256
#define HH 128
#define OUT_D 64
#define DEPTH 3

typedef unsigned short u16;
typedef __bf16  bf16x8 __attribute__((ext_vector_type(8)));
typedef short   short8 __attribute__((ext_vector_type(8)));
typedef float   f32x4  __attribute__((ext_vector_type(4)));

__device__ __forceinline__ u16 f2b(float f){
    unsigned u = __float_as_uint(f);
    u += 0x7fff + ((u>>16)&1);            // round-to-nearest-even
    return (u16)(u>>16);
}
__device__ __forceinline__ float b2f(u16 h){ return __uint_as_float(((unsigned)h)<<16); }
__device__ __forceinline__ float sigm(float x){ return 1.f/(1.f+expf(-x)); }

// ================= A-resident register GEMM =================
// Block = 64 A-rows x M out-cols. A staged ONCE into LDS (XOR-swizzled), then a
// barrier-free k-loop: 4 ds_read_b128 (A frags, shared across col-tiles) +
// CT coalesced 1KB B loads (fragment-packed, L2-resident) + 4*CT MFMAs per k-step.
// Wave w owns col-tiles ctg = j*WAVES + w  (for GATES: j = gate index, so the
// c/mu epilogue is wave-local). In-place mu safe: block touches only its 64 rows.
enum { EPI_BF=0, EPI_RELU=1, EPI_ZEL=2, EPI_GATES_FIRST=3, EPI_GATES=4 };

template<int EPI, int WAVES, int CT, int K, typename TA>
__global__ __launch_bounds__(WAVES*64, 4) void rgemm_k(
    const TA* __restrict__ A1, const u16* __restrict__ A2,
    const u16* __restrict__ Bp,
    const float* __restrict__ b1,   // bias | al | igb
    const float* __restrict__ b2,   // ar | stb
    const float* __restrict__ b3,   // fgb
    const float* __restrict__ b4,   // ogb
    void* __restrict__ Out,         // u16 z/mu  or  float (RELU)
    float* __restrict__ aux1,       // el | cbuf
    float* __restrict__ aux2,       // er
    int Nrows)
{
    constexpr int TH = WAVES*64;
    constexpr int KS = K/32;
    constexpr int M  = WAVES*CT*16;
    constexpr bool GATES = (EPI==EPI_GATES || EPI==EPI_GATES_FIRST);
    __shared__ u16 As[64*K];
    __shared__ float elp[(EPI==EPI_ZEL)?64*WAVES:1];
    __shared__ float erp[(EPI==EPI_ZEL)?64*WAVES:1];

    const int tid = threadIdx.x;
    const int rb  = blockIdx.x*64;

    // ---- stage A (once) ----
    constexpr int CHUNKS = 64*K/(TH*8);
    #pragma unroll
    for (int c = 0; c < CHUNKS; ++c) {
        int h = (tid + c*TH)*8;
        int row = h / K, kk = h % K;
        int grow = rb + row; if (grow >= Nrows) grow = Nrows-1;
        short8 v;
        if constexpr (std::is_same<TA,float>::value) {
            const float* p = A1 + (size_t)grow*K + kk;
            float4 x0 = *(const float4*)p;
            float4 x1 = *(const float4*)(p+4);
            v[0]=(short)f2b(x0.x); v[1]=(short)f2b(x0.y); v[2]=(short)f2b(x0.z); v[3]=(short)f2b(x0.w);
            v[4]=(short)f2b(x1.x); v[5]=(short)f2b(x1.y); v[6]=(short)f2b(x1.z); v[7]=(short)f2b(x1.w);
        } else if constexpr (GATES) {
            const u16* p = (kk < HH) ? (A1 + (size_t)grow*HH + kk)
                                     : (A2 + (size_t)grow*HH + (kk-HH));
            v = *(const short8*)p;
        } else {
            v = *(const short8*)(A1 + (size_t)grow*K + kk);
        }
        int byte = row*(K*2) + ((kk*2) ^ ((row&7)<<4));
        *(short8*)((char*)As + byte) = v;
    }
    __syncthreads();

    // ---- barrier-free k-loop ----
    const int lane = tid & 63, w = tid >> 6;
    const int ml = lane & 15, ksel = lane >> 4;
    f32x4 acc[4][CT] = {};
    for (int ks = 0; ks < KS; ++ks) {
        bf16x8 a[4];
        #pragma unroll
        for (int rt = 0; rt < 4; ++rt) {
            int row = rt*16 + ml;
            int byte = row*(K*2) + (((ks*32 + ksel*8)*2) ^ ((row&7)<<4));
            a[rt] = *(const bf16x8*)((const char*)As + byte);
        }
        #pragma unroll
        for (int j = 0; j < CT; ++j) {
            int ctg = j*WAVES + w;
            bf16x8 b = *(const bf16x8*)(Bp + (((size_t)(ctg*KS + ks))<<9) + lane*8);
            #pragma unroll
            for (int rt = 0; rt < 4; ++rt)
                acc[rt][j] = __builtin_amdgcn_mfma_f32_16x16x32_bf16(a[rt], b, acc[rt][j], 0,0,0);
        }
    }

    // ---- epilogues ----
    if constexpr (EPI==EPI_BF || EPI==EPI_RELU) {
        #pragma unroll
        for (int rt = 0; rt < 4; ++rt)
        #pragma unroll
        for (int r = 0; r < 4; ++r) {
            int row = rb + rt*16 + ksel*4 + r;
            if (row >= Nrows) continue;
            #pragma unroll
            for (int j = 0; j < CT; ++j) {
                int gc = (j*WAVES + w)*16 + ml;
                float vv = acc[rt][j][r] + b1[gc];
                if (EPI==EPI_BF) ((u16*)Out)[(size_t)row*M + gc]   = f2b(vv);
                else             ((float*)Out)[(size_t)row*M + gc] = fmaxf(vv, 0.f);
            }
        }
    } else if constexpr (EPI==EPI_ZEL) {
        float pel[4][4] = {}, per[4][4] = {};
        #pragma unroll
        for (int j = 0; j < CT; ++j) {
            int gc = (j*WAVES + w)*16 + ml;
            float alc = b1[gc], arc = b2[gc];
            #pragma unroll
            for (int rt = 0; rt < 4; ++rt)
            #pragma unroll
            for (int r = 0; r < 4; ++r) {
                int row = rb + rt*16 + ksel*4 + r;
                float vv = acc[rt][j][r];
                if (row < Nrows) ((u16*)Out)[(size_t)row*HH + gc] = f2b(vv);
                pel[rt][r] = fmaf(vv, alc, pel[rt][r]);
                per[rt][r] = fmaf(vv, arc, per[rt][r]);
            }
        }
        #pragma unroll
        for (int msk = 1; msk < 16; msk <<= 1)
            #pragma unroll
            for (int rt = 0; rt < 4; ++rt)
            #pragma unroll
            for (int r = 0; r < 4; ++r) {
                pel[rt][r] += __shfl_xor(pel[rt][r], msk);
                per[rt][r] += __shfl_xor(per[rt][r], msk);
            }
        if (ml == 0) {
            #pragma unroll
            for (int rt = 0; rt < 4; ++rt)
            #pragma unroll
            for (int r = 0; r < 4; ++r) {
                int lr = rt*16 + ksel*4 + r;
                elp[lr*WAVES + w] = pel[rt][r];
                erp[lr*WAVES + w] = per[rt][r];
            }
        }
        __syncthreads();
        if (tid < 64) {
            int row = rb + tid;
            if (row < Nrows) {
                float s1 = 0.f, s2 = 0.f;
                #pragma unroll
                for (int wv = 0; wv < WAVES; ++wv) { s1 += elp[tid*WAVES+wv]; s2 += erp[tid*WAVES+wv]; }
                aux1[row] = s1; aux2[row] = s2;
            }
        }
    } else {   // GATES: j = gate (ig, st, fg, og), wave-local combine
        #pragma unroll
        for (int rt = 0; rt < 4; ++rt)
        #pragma unroll
        for (int r = 0; r < 4; ++r) {
            int row = rb + rt*16 + ksel*4 + r;
            if (row >= Nrows) continue;
            int gcg = w*16 + ml;
            size_t o = (size_t)row*HH + gcg;
            float ig = sigm (acc[rt][0][r] + b1[gcg]);
            float st = tanhf(acc[rt][1][r] + b2[gcg]);
            float fg = sigm (acc[rt][2][r] + b3[gcg]);
            float og = sigm (acc[rt][3][r] + b4[gcg]);
            float P  = ig * st;
            float cn = (EPI==EPI_GATES_FIRST) ? P : fmaf(fg, aux1[o], P);
            aux1[o] = cn;
            ((u16*)Out)[o] = f2b(og * tanhf(cn));
        }
    }
}

// ================= weight pack: W[k][Mc] f32 -> fragment-packed bf16 =================
// dst[((ct*KS + ks)*64 + lane)*8 + i] = W[(ks*32 + (lane>>4)*8 + i)][ct*16 + (lane&15)]
struct PK  { const float* s; u16* d; int K; int Mc; };
struct PKs { PK t[17]; };
__global__ __launch_bounds__(256) void pack_k(PKs ps){
    const PK t = ps.t[blockIdx.y];
    int o = blockIdx.x*256 + threadIdx.x;
    if (o >= t.K * t.Mc) return;
    int i = o & 7, lane = (o>>3) & 63, rst = o >> 9;
    int KS = t.K >> 5;
    int ks = rst % KS, ct = rst / KS;
    int col = ct*16 + (lane & 15);
    int k   = ks*32 + (lane>>4)*8 + i;
    t.d[o] = f2b(t.s[(size_t)k*t.Mc + col]);
}

// ================= per-node attention softmax (CSR order) =================
__global__ __launch_bounds__(256) void attn_k(
    const float* __restrict__ el, const float* __restrict__ er,
    const int* __restrict__ srcs, const int* __restrict__ rp, const int* __restrict__ deg,
    float* __restrict__ alpha)
{
    int n = blockIdx.x*4 + (threadIdx.x>>6);
    if (n >= NN) return;
    int lane = threadIdx.x & 63;
    int start = rp[n], cnt = deg[n];
    float ern = er[n];
    float m = -1e30f;
    for (int i=lane; i<cnt; i+=64) {
        float v = el[srcs[start+i]] + ern;
        v = v >= 0.f ? v : 0.2f*v;
        alpha[start+i] = v;
        m = fmaxf(m, v);
    }
    #pragma unroll
    for (int off=1; off<64; off<<=1) m = fmaxf(m, __shfl_xor(m, off));
    float s = 0.f;
    for (int i=lane; i<cnt; i+=64) s += expf(alpha[start+i] - m);
    #pragma unroll
    for (int off=1; off<64; off<<=1) s += __shfl_xor(s, off);
    float inv = 1.f / fmaxf(s, 1e-16f);
    for (int i=lane; i<cnt; i+=64) alpha[start+i] = expf(alpha[start+i] - m) * inv;
}

// ================= weighted gather =================
__global__ __launch_bounds__(256) void agg_k(
    const u16* __restrict__ z, const float* __restrict__ alpha,
    const int* __restrict__ srcs, const int* __restrict__ rp, const int* __restrict__ deg,
    const float* __restrict__ bias, u16* __restrict__ hout)
{
    int n = blockIdx.x*4 + (threadIdx.x>>6);
    if (n >= NN) return;
    int lane = threadIdx.x & 63;
    int start = rp[n], cnt = deg[n];
    const int slot = lane >> 4;
    const int ch   = (lane & 15) * 8;
    float acc[8] = {};
    for (int i = slot; i < cnt; i += 4) {
        int p = start + i;
        float wgt = alpha[p];
        short8 v = *(const short8*)(z + (size_t)srcs[p]*HH + ch);
        #pragma unroll
        for (int j=0;j<8;j++) acc[j] = fmaf(wgt, b2f((u16)v[j]), acc[j]);
    }
    #pragma unroll
    for (int j=0;j<8;j++){ acc[j] += __shfl_xor(acc[j],16); acc[j] += __shfl_xor(acc[j],32); }
    if (slot == 0) {
        short8 o8;
        #pragma unroll
        for (int j=0;j<8;j++) o8[j] = (short)f2b(tanhf(acc[j] + bias[ch+j]));
        *(short8*)(hout + (size_t)n*HH + ch) = o8;
    }
}

// ================= CSR build (by dst) =================
__global__ void count_k(const int* __restrict__ dst, int* __restrict__ deg){
    int e = blockIdx.x*256 + threadIdx.x;
    if (e < EE) atomicAdd(&deg[dst[e]], 1);
}
__global__ __launch_bounds__(256) void scan1_k(const int* __restrict__ deg, int* __restrict__ rp,
                                               int* __restrict__ bsum, int n){
    __shared__ int s[256];
    int t = threadIdx.x, idx = blockIdx.x*256 + t;
    int v = (idx < n) ? deg[idx] : 0;
    s[t] = v; __syncthreads();
    for (int off=1; off<256; off<<=1){ int x = (t>=off)? s[t-off] : 0; __syncthreads(); s[t] += x; __syncthreads(); }
    if (idx < n) rp[idx] = s[t] - v;
    if (t == 255) bsum[blockIdx.x] = s[255];
}
__global__ __launch_bounds__(256) void scan2_k(int* __restrict__ bsum, int nb){
    __shared__ int s[256];
    int t = threadIdx.x;
    int v = (t < nb) ? bsum[t] : 0;
    s[t] = v; __syncthreads();
    for (int off=1; off<256; off<<=1){ int x = (t>=off)? s[t-off] : 0; __syncthreads(); s[t] += x; __syncthreads(); }
    if (t < nb) bsum[t] = s[t] - v;
}
__global__ void scan3_k(int* __restrict__ rp, const int* __restrict__ bsum, int n){
    int idx = blockIdx.x*256 + threadIdx.x;
    if (idx < n) rp[idx] += bsum[blockIdx.x];
}
__global__ void fill_k(const int* __restrict__ dst, const int* __restrict__ src,
                       const int* __restrict__ rp, int* __restrict__ cursor,
                       int* __restrict__ srcs){
    int e = blockIdx.x*256 + threadIdx.x;
    if (e >= EE) return;
    int d = dst[e];
    int pos = rp[d] + atomicAdd(&cursor[d], 1);
    srcs[pos] = src[e];
}

extern "C" void kernel_launch(void* const* d_in, const int* in_sizes, int n_in,
                              void* d_out, int out_size, void* d_ws, size_t ws_size,
                              hipStream_t stream)
{
    const float* x    = (const float*)d_in[0];
    const int*   src  = (const int*)d_in[1];
    const int*   dst  = (const int*)d_in[2];
    const float* wxW  = (const float*)d_in[3];
    const float* wxb  = (const float*)d_in[4];
    const float* gatW = (const float*)d_in[5];
    const float* gatb = (const float*)d_in[6];
    const float* attl = (const float*)d_in[7];
    const float* attr = (const float*)d_in[8];
    const float* igW  = (const float*)d_in[9];
    const float* igb  = (const float*)d_in[10];
    const float* fgW  = (const float*)d_in[11];
    const float* fgb  = (const float*)d_in[12];
    const float* ogW  = (const float*)d_in[13];
    const float* ogb  = (const float*)d_in[14];
    const float* stW  = (const float*)d_in[15];
    const float* stb  = (const float*)d_in[16];
    const float* outW = (const float*)d_in[17];
    const float* outb = (const float*)d_in[18];

    char* w = (char*)d_ws;
    auto alloc = [&](size_t bytes)->char* { char* p = w; w += (bytes + 255) & ~(size_t)255; return p; };
    const size_t NH = (size_t)NN * HH;
    u16*   muB    = (u16*)alloc(NH*2);            // h0 -> mu (bf16 master)
    u16*   zB     = (u16*)alloc(NH*2);
    u16*   coll0  = (u16*)alloc(NH*2);
    u16*   coll1  = (u16*)alloc(NH*2);
    u16*   coll2  = (u16*)alloc(NH*2);
    float* cbuf   = (float*)alloc(NH*4);
    float* el     = (float*)alloc((size_t)NN*4);
    float* er     = (float*)alloc((size_t)NN*4);
    float* alpha  = (float*)alloc((size_t)EE*4);
    int*   deg    = (int*)alloc((size_t)NN*4);
    int*   cursor = (int*)alloc((size_t)NN*4);
    int*   rp     = (int*)alloc((size_t)NN*4);
    int*   bsum   = (int*)alloc(256*4);
    int*   srcs   = (int*)alloc((size_t)EE*4);
    u16*   bpool  = (u16*)alloc(483328*2);
    u16* wxP   = bpool;              // 32768 halves
    u16* gatP  = bpool + 32768;      // 3 x 16384
    u16* gateP = bpool + 81920;      // 3 x 131072  (= 4 gates x 32768, order ig|st|fg|og)
    u16* outP  = bpool + 475136;     // 8192
    u16* coll[3] = {coll0, coll1, coll2};

    // ---- pack all 17 weight matrices into MFMA-fragment order ----
    PKs ps;
    ps.t[0] = {wxW, wxP, IN_D, HH};
    for (int i=0;i<3;i++) ps.t[1+i]  = {gatW + (size_t)i*HH*HH,   gatP  + i*16384,           HH,   HH};
    for (int i=0;i<3;i++) ps.t[4+i]  = {igW  + (size_t)i*2*HH*HH, gateP + i*131072,          2*HH, HH};
    for (int i=0;i<3;i++) ps.t[7+i]  = {stW  + (size_t)i*2*HH*HH, gateP + i*131072 + 32768,  2*HH, HH};
    for (int i=0;i<3;i++) ps.t[10+i] = {fgW  + (size_t)i*2*HH*HH, gateP + i*131072 + 65536,  2*HH, HH};
    for (int i=0;i<3;i++) ps.t[13+i] = {ogW  + (size_t)i*2*HH*HH, gateP + i*131072 + 98304,  2*HH, HH};
    ps.t[16] = {outW, outP, HH, OUT_D};
    pack_k<<<dim3(128,17), 256, 0, stream>>>(ps);

    // ---- CSR by dst ----
    hipMemsetAsync(deg, 0, (size_t)NN*4, stream);
    hipMemsetAsync(cursor, 0, (size_t)NN*4, stream);
    count_k<<<(EE+255)/256, 256, 0, stream>>>(dst, deg);
    int nb = (NN+255)/256;
    scan1_k<<<nb, 256, 0, stream>>>(deg, rp, bsum, NN);
    scan2_k<<<1, 256, 0, stream>>>(bsum, nb);
    scan3_k<<<nb, 256, 0, stream>>>(rp, bsum, NN);
    fill_k<<<(EE+255)/256, 256, 0, stream>>>(dst, src, rp, cursor, srcs);

    const int gN = (NN + 63) / 64;   // 782 blocks
    const int gA = (NN + 3) / 4;     // 12500 blocks

    // ---- h0 = x @ wxW + wxb -> muB ----
    rgemm_k<EPI_BF,4,2,IN_D,float><<<gN, 256, 0, stream>>>(
        x, nullptr, wxP, wxb, nullptr, nullptr, nullptr, muB, nullptr, nullptr, NN);

    // ---- GAT layers ----
    const u16* hin = muB;
    for (int i = 0; i < DEPTH; ++i) {
        rgemm_k<EPI_ZEL,4,2,HH,u16><<<gN, 256, 0, stream>>>(
            hin, nullptr, gatP + i*16384, attl + i*HH, attr + i*HH, nullptr, nullptr,
            zB, el, er, NN);
        attn_k<<<gA, 256, 0, stream>>>(el, er, srcs, rp, deg, alpha);
        agg_k<<<gA, 256, 0, stream>>>(zB, alpha, srcs, rp, deg, gatb + i*HH, coll[i]);
        hin = coll[i];
    }

    // ---- depth: fused 4-gate + c/mu update ----
    rgemm_k<EPI_GATES_FIRST,8,4,2*HH,u16><<<gN, 512, 0, stream>>>(
        coll[0], muB, gateP, igb, stb, fgb, ogb, muB, cbuf, nullptr, NN);
    for (int i = 1; i < DEPTH; ++i)
        rgemm_k<EPI_GATES,8,4,2*HH,u16><<<gN, 512, 0, stream>>>(
            coll[i], muB, gateP + i*131072, igb + i*HH, stb + i*HH, fgb + i*HH, ogb + i*HH,
            muB, cbuf, nullptr, NN);

    // ---- out = relu(mu @ outW + outb) -> f32 ----
    rgemm_k<EPI_RELU,4,1,HH,u16><<<gN, 256, 0, stream>>>(
        muB, nullptr, outP, outb, nullptr, nullptr, nullptr, (float*)d_out, nullptr, nullptr, NN);
}

// Round 7
// 439.185 us; speedup vs baseline: 1.7484x; 1.1828x over previous
//
#include <hip/hip_runtime.h>
#include <math.h>
#include <type_traits>

#define NN 50000
#define EE 800000
#define IN_D 256
#define HH 128
#define OUT_D 64
#define DEPTH 3

typedef unsigned short u16;
typedef __bf16  bf16x8 __attribute__((ext_vector_type(8)));
typedef short   short8 __attribute__((ext_vector_type(8)));
typedef float   f32x4  __attribute__((ext_vector_type(4)));

__device__ __forceinline__ u16 f2b(float f){
    unsigned u = __float_as_uint(f);
    u += 0x7fff + ((u>>16)&1);            // round-to-nearest-even
    return (u16)(u>>16);
}
__device__ __forceinline__ float b2f(u16 h){ return __uint_as_float(((unsigned)h)<<16); }

#define LOG2E 1.4426950408889634f
#if __has_builtin(__builtin_amdgcn_exp2f)
__device__ __forceinline__ float fexp2(float x){ return __builtin_amdgcn_exp2f(x); }
#else
__device__ __forceinline__ float fexp2(float x){ return exp2f(x); }
#endif
#if __has_builtin(__builtin_amdgcn_rcpf)
__device__ __forceinline__ float frcp(float x){ return __builtin_amdgcn_rcpf(x); }
#else
__device__ __forceinline__ float frcp(float x){ return 1.f/x; }
#endif
// sigmoid(x) = 1/(1+2^(-x*log2e))
__device__ __forceinline__ float sigm(float x){ return frcp(1.f + fexp2(-x*LOG2E)); }
// tanh(x) = sign(x) * (1-u)/(1+u), u = 2^(-2|x|*log2e)
__device__ __forceinline__ float ftanh(float x){
    float ax = fabsf(x);
    float u = fexp2(ax * (-2.f*LOG2E));
    float r = (1.f - u) * frcp(1.f + u);
    return copysignf(r, x);
}

// ================= A-resident register GEMM =================
// Block = 64 A-rows x M out-cols. A staged ONCE into LDS (XOR-swizzled), then a
// barrier-free fully-unrolled k-loop: 4 ds_read_b128 (A frags) + CT coalesced
// 1KB B loads (fragment-packed, L2-resident) + 4*CT MFMAs per k-step.
// Wave w owns col-tiles ctg = j*WAVES + w (GATES: j = gate index -> wave-local epilogue).
enum { EPI_BF=0, EPI_RELU=1, EPI_ZEL=2, EPI_GATES_FIRST=3, EPI_GATES=4 };

template<int EPI, int WAVES, int CT, int K, typename TA>
__global__ __launch_bounds__(WAVES*64, 4) void rgemm_k(
    const TA* __restrict__ A1, const u16* __restrict__ A2,
    const u16* __restrict__ Bp,
    const float* __restrict__ b1,   // bias | al | igb
    const float* __restrict__ b2,   // ar | stb
    const float* __restrict__ b3,   // fgb
    const float* __restrict__ b4,   // ogb
    void* __restrict__ Out,         // u16 z/mu  or  float (RELU)
    float* __restrict__ aux1,       // el | cbuf
    float* __restrict__ aux2,       // er
    int Nrows)
{
    constexpr int TH = WAVES*64;
    constexpr int KS = K/32;
    constexpr int M  = WAVES*CT*16;
    constexpr bool GATES = (EPI==EPI_GATES || EPI==EPI_GATES_FIRST);
    __shared__ u16 As[64*K];
    __shared__ float elp[(EPI==EPI_ZEL)?64*WAVES:1];
    __shared__ float erp[(EPI==EPI_ZEL)?64*WAVES:1];

    const int tid = threadIdx.x;
    const int rb  = blockIdx.x*64;

    // ---- stage A (once) ----
    constexpr int CHUNKS = 64*K/(TH*8);
    #pragma unroll
    for (int c = 0; c < CHUNKS; ++c) {
        int h = (tid + c*TH)*8;
        int row = h / K, kk = h % K;
        int grow = rb + row; if (grow >= Nrows) grow = Nrows-1;
        short8 v;
        if constexpr (std::is_same<TA,float>::value) {
            const float* p = A1 + (size_t)grow*K + kk;
            float4 x0 = *(const float4*)p;
            float4 x1 = *(const float4*)(p+4);
            v[0]=(short)f2b(x0.x); v[1]=(short)f2b(x0.y); v[2]=(short)f2b(x0.z); v[3]=(short)f2b(x0.w);
            v[4]=(short)f2b(x1.x); v[5]=(short)f2b(x1.y); v[6]=(short)f2b(x1.z); v[7]=(short)f2b(x1.w);
        } else if constexpr (GATES) {
            const u16* p = (kk < HH) ? (A1 + (size_t)grow*HH + kk)
                                     : (A2 + (size_t)grow*HH + (kk-HH));
            v = *(const short8*)p;
        } else {
            v = *(const short8*)(A1 + (size_t)grow*K + kk);
        }
        int byte = row*(K*2) + ((kk*2) ^ ((row&7)<<4));
        *(short8*)((char*)As + byte) = v;
    }
    __syncthreads();

    // ---- barrier-free k-loop (fully unrolled) ----
    const int lane = tid & 63, w = tid >> 6;
    const int ml = lane & 15, ksel = lane >> 4;
    f32x4 acc[4][CT] = {};
    #pragma unroll
    for (int ks = 0; ks < KS; ++ks) {
        bf16x8 a[4];
        #pragma unroll
        for (int rt = 0; rt < 4; ++rt) {
            int row = rt*16 + ml;
            int byte = row*(K*2) + (((ks*32 + ksel*8)*2) ^ ((row&7)<<4));
            a[rt] = *(const bf16x8*)((const char*)As + byte);
        }
        #pragma unroll
        for (int j = 0; j < CT; ++j) {
            int ctg = j*WAVES + w;
            bf16x8 b = *(const bf16x8*)(Bp + (((size_t)(ctg*KS + ks))<<9) + lane*8);
            #pragma unroll
            for (int rt = 0; rt < 4; ++rt)
                acc[rt][j] = __builtin_amdgcn_mfma_f32_16x16x32_bf16(a[rt], b, acc[rt][j], 0,0,0);
        }
    }

    // ---- epilogues ----
    if constexpr (EPI==EPI_BF || EPI==EPI_RELU) {
        #pragma unroll
        for (int rt = 0; rt < 4; ++rt)
        #pragma unroll
        for (int r = 0; r < 4; ++r) {
            int row = rb + rt*16 + ksel*4 + r;
            if (row >= Nrows) continue;
            #pragma unroll
            for (int j = 0; j < CT; ++j) {
                int gc = (j*WAVES + w)*16 + ml;
                float vv = acc[rt][j][r] + b1[gc];
                if (EPI==EPI_BF) ((u16*)Out)[(size_t)row*M + gc]   = f2b(vv);
                else             ((float*)Out)[(size_t)row*M + gc] = fmaxf(vv, 0.f);
            }
        }
    } else if constexpr (EPI==EPI_ZEL) {
        float pel[4][4] = {}, per[4][4] = {};
        #pragma unroll
        for (int j = 0; j < CT; ++j) {
            int gc = (j*WAVES + w)*16 + ml;
            float alc = b1[gc], arc = b2[gc];
            #pragma unroll
            for (int rt = 0; rt < 4; ++rt)
            #pragma unroll
            for (int r = 0; r < 4; ++r) {
                int row = rb + rt*16 + ksel*4 + r;
                float vv = acc[rt][j][r];
                if (row < Nrows) ((u16*)Out)[(size_t)row*HH + gc] = f2b(vv);
                pel[rt][r] = fmaf(vv, alc, pel[rt][r]);
                per[rt][r] = fmaf(vv, arc, per[rt][r]);
            }
        }
        #pragma unroll
        for (int msk = 1; msk < 16; msk <<= 1)
            #pragma unroll
            for (int rt = 0; rt < 4; ++rt)
            #pragma unroll
            for (int r = 0; r < 4; ++r) {
                pel[rt][r] += __shfl_xor(pel[rt][r], msk);
                per[rt][r] += __shfl_xor(per[rt][r], msk);
            }
        if (ml == 0) {
            #pragma unroll
            for (int rt = 0; rt < 4; ++rt)
            #pragma unroll
            for (int r = 0; r < 4; ++r) {
                int lr = rt*16 + ksel*4 + r;
                elp[lr*WAVES + w] = pel[rt][r];
                erp[lr*WAVES + w] = per[rt][r];
            }
        }
        __syncthreads();
        if (tid < 64) {
            int row = rb + tid;
            if (row < Nrows) {
                float s1 = 0.f, s2 = 0.f;
                #pragma unroll
                for (int wv = 0; wv < WAVES; ++wv) { s1 += elp[tid*WAVES+wv]; s2 += erp[tid*WAVES+wv]; }
                aux1[row] = s1; aux2[row] = s2;
            }
        }
    } else {   // GATES: j = gate (ig, st, fg, og), wave-local combine
        #pragma unroll
        for (int rt = 0; rt < 4; ++rt)
        #pragma unroll
        for (int r = 0; r < 4; ++r) {
            int row = rb + rt*16 + ksel*4 + r;
            if (row >= Nrows) continue;
            int gcg = w*16 + ml;
            size_t o = (size_t)row*HH + gcg;
            float ig = sigm (acc[rt][0][r] + b1[gcg]);
            float st = ftanh(acc[rt][1][r] + b2[gcg]);
            float fg = sigm (acc[rt][2][r] + b3[gcg]);
            float og = sigm (acc[rt][3][r] + b4[gcg]);
            float P  = ig * st;
            float cn = (EPI==EPI_GATES_FIRST) ? P : fmaf(fg, aux1[o], P);
            aux1[o] = cn;
            ((u16*)Out)[o] = f2b(og * ftanh(cn));
        }
    }
}

// ================= weight pack: W[k][Mc] f32 -> fragment-packed bf16 =================
struct PK  { const float* s; u16* d; int K; int Mc; };
struct PKs { PK t[17]; };
__global__ __launch_bounds__(256) void pack_k(PKs ps){
    const PK t = ps.t[blockIdx.y];
    int o = blockIdx.x*256 + threadIdx.x;
    if (o >= t.K * t.Mc) return;
    int i = o & 7, lane = (o>>3) & 63, rst = o >> 9;
    int KS = t.K >> 5;
    int ks = rst % KS, ct = rst / KS;
    int col = ct*16 + (lane & 15);
    int k   = ks*32 + (lane>>4)*8 + i;
    t.d[o] = f2b(t.s[(size_t)k*t.Mc + col]);
}

// ================= per-node attention softmax (CSR order) =================
__global__ __launch_bounds__(256) void attn_k(
    const float* __restrict__ el, const float* __restrict__ er,
    const int* __restrict__ srcs, const int* __restrict__ rp, const int* __restrict__ deg,
    float* __restrict__ alpha)
{
    int n = blockIdx.x*4 + (threadIdx.x>>6);
    if (n >= NN) return;
    int lane = threadIdx.x & 63;
    int start = rp[n], cnt = deg[n];
    float ern = er[n];
    float m = -1e30f;
    for (int i=lane; i<cnt; i+=64) {
        float v = el[srcs[start+i]] + ern;
        v = v >= 0.f ? v : 0.2f*v;
        alpha[start+i] = v;
        m = fmaxf(m, v);
    }
    #pragma unroll
    for (int off=1; off<64; off<<=1) m = fmaxf(m, __shfl_xor(m, off));
    float s = 0.f;
    for (int i=lane; i<cnt; i+=64) s += fexp2((alpha[start+i] - m)*LOG2E);
    #pragma unroll
    for (int off=1; off<64; off<<=1) s += __shfl_xor(s, off);
    float inv = frcp(fmaxf(s, 1e-16f));
    for (int i=lane; i<cnt; i+=64) alpha[start+i] = fexp2((alpha[start+i] - m)*LOG2E) * inv;
}

// ================= weighted gather =================
__global__ __launch_bounds__(256) void agg_k(
    const u16* __restrict__ z, const float* __restrict__ alpha,
    const int* __restrict__ srcs, const int* __restrict__ rp, const int* __restrict__ deg,
    const float* __restrict__ bias, u16* __restrict__ hout)
{
    int n = blockIdx.x*4 + (threadIdx.x>>6);
    if (n >= NN) return;
    int lane = threadIdx.x & 63;
    int start = rp[n], cnt = deg[n];
    const int slot = lane >> 4;
    const int ch   = (lane & 15) * 8;
    float acc[8] = {};
    for (int i = slot; i < cnt; i += 4) {
        int p = start + i;
        float wgt = alpha[p];
        short8 v = *(const short8*)(z + (size_t)srcs[p]*HH + ch);
        #pragma unroll
        for (int j=0;j<8;j++) acc[j] = fmaf(wgt, b2f((u16)v[j]), acc[j]);
    }
    #pragma unroll
    for (int j=0;j<8;j++){ acc[j] += __shfl_xor(acc[j],16); acc[j] += __shfl_xor(acc[j],32); }
    if (slot == 0) {
        short8 o8;
        #pragma unroll
        for (int j=0;j<8;j++) o8[j] = (short)f2b(ftanh(acc[j] + bias[ch+j]));
        *(short8*)(hout + (size_t)n*HH + ch) = o8;
    }
}

// ================= CSR build (by dst) =================
__global__ void count_k(const int* __restrict__ dst, int* __restrict__ deg){
    int e = blockIdx.x*256 + threadIdx.x;
    if (e < EE) atomicAdd(&deg[dst[e]], 1);
}
__global__ __launch_bounds__(256) void scan1_k(const int* __restrict__ deg, int* __restrict__ rp,
                                               int* __restrict__ bsum, int n){
    __shared__ int s[256];
    int t = threadIdx.x, idx = blockIdx.x*256 + t;
    int v = (idx < n) ? deg[idx] : 0;
    s[t] = v; __syncthreads();
    for (int off=1; off<256; off<<=1){ int x = (t>=off)? s[t-off] : 0; __syncthreads(); s[t] += x; __syncthreads(); }
    if (idx < n) rp[idx] = s[t] - v;
    if (t == 255) bsum[blockIdx.x] = s[255];
}
__global__ __launch_bounds__(256) void scan2_k(int* __restrict__ bsum, int nb){
    __shared__ int s[256];
    int t = threadIdx.x;
    int v = (t < nb) ? bsum[t] : 0;
    s[t] = v; __syncthreads();
    for (int off=1; off<256; off<<=1){ int x = (t>=off)? s[t-off] : 0; __syncthreads(); s[t] += x; __syncthreads(); }
    if (t < nb) bsum[t] = s[t] - v;
}
__global__ void scan3_k(int* __restrict__ rp, const int* __restrict__ bsum, int n){
    int idx = blockIdx.x*256 + threadIdx.x;
    if (idx < n) rp[idx] += bsum[blockIdx.x];
}
__global__ void fill_k(const int* __restrict__ dst, const int* __restrict__ src,
                       const int* __restrict__ rp, int* __restrict__ cursor,
                       int* __restrict__ srcs){
    int e = blockIdx.x*256 + threadIdx.x;
    if (e >= EE) return;
    int d = dst[e];
    int pos = rp[d] + atomicAdd(&cursor[d], 1);
    srcs[pos] = src[e];
}

extern "C" void kernel_launch(void* const* d_in, const int* in_sizes, int n_in,
                              void* d_out, int out_size, void* d_ws, size_t ws_size,
                              hipStream_t stream)
{
    const float* x    = (const float*)d_in[0];
    const int*   src  = (const int*)d_in[1];
    const int*   dst  = (const int*)d_in[2];
    const float* wxW  = (const float*)d_in[3];
    const float* wxb  = (const float*)d_in[4];
    const float* gatW = (const float*)d_in[5];
    const float* gatb = (const float*)d_in[6];
    const float* attl = (const float*)d_in[7];
    const float* attr = (const float*)d_in[8];
    const float* igW  = (const float*)d_in[9];
    const float* igb  = (const float*)d_in[10];
    const float* fgW  = (const float*)d_in[11];
    const float* fgb  = (const float*)d_in[12];
    const float* ogW  = (const float*)d_in[13];
    const float* ogb  = (const float*)d_in[14];
    const float* stW  = (const float*)d_in[15];
    const float* stb  = (const float*)d_in[16];
    const float* outW = (const float*)d_in[17];
    const float* outb = (const float*)d_in[18];

    char* w = (char*)d_ws;
    auto alloc = [&](size_t bytes)->char* { char* p = w; w += (bytes + 255) & ~(size_t)255; return p; };
    const size_t NH = (size_t)NN * HH;
    u16*   muB    = (u16*)alloc(NH*2);            // h0 -> mu (bf16 master)
    u16*   zB     = (u16*)alloc(NH*2);
    u16*   coll0  = (u16*)alloc(NH*2);
    u16*   coll1  = (u16*)alloc(NH*2);
    u16*   coll2  = (u16*)alloc(NH*2);
    float* cbuf   = (float*)alloc(NH*4);
    float* el     = (float*)alloc((size_t)NN*4);
    float* er     = (float*)alloc((size_t)NN*4);
    float* alpha  = (float*)alloc((size_t)EE*4);
    int*   deg    = (int*)alloc((size_t)NN*4);
    int*   cursor = (int*)alloc((size_t)NN*4);
    int*   rp     = (int*)alloc((size_t)NN*4);
    int*   bsum   = (int*)alloc(256*4);
    int*   srcs   = (int*)alloc((size_t)EE*4);
    u16*   bpool  = (u16*)alloc(483328*2);
    u16* wxP   = bpool;              // 32768 halves
    u16* gatP  = bpool + 32768;      // 3 x 16384
    u16* gateP = bpool + 81920;      // 3 x 131072  (= 4 gates x 32768, order ig|st|fg|og)
    u16* outP  = bpool + 475136;     // 8192
    u16* coll[3] = {coll0, coll1, coll2};

    // ---- pack all 17 weight matrices into MFMA-fragment order ----
    PKs ps;
    ps.t[0] = {wxW, wxP, IN_D, HH};
    for (int i=0;i<3;i++) ps.t[1+i]  = {gatW + (size_t)i*HH*HH,   gatP  + i*16384,           HH,   HH};
    for (int i=0;i<3;i++) ps.t[4+i]  = {igW  + (size_t)i*2*HH*HH, gateP + i*131072,          2*HH, HH};
    for (int i=0;i<3;i++) ps.t[7+i]  = {stW  + (size_t)i*2*HH*HH, gateP + i*131072 + 32768,  2*HH, HH};
    for (int i=0;i<3;i++) ps.t[10+i] = {fgW  + (size_t)i*2*HH*HH, gateP + i*131072 + 65536,  2*HH, HH};
    for (int i=0;i<3;i++) ps.t[13+i] = {ogW  + (size_t)i*2*HH*HH, gateP + i*131072 + 98304,  2*HH, HH};
    ps.t[16] = {outW, outP, HH, OUT_D};
    pack_k<<<dim3(128,17), 256, 0, stream>>>(ps);

    // ---- CSR by dst ----
    hipMemsetAsync(deg, 0, (size_t)NN*4, stream);
    hipMemsetAsync(cursor, 0, (size_t)NN*4, stream);
    count_k<<<(EE+255)/256, 256, 0, stream>>>(dst, deg);
    int nb = (NN+255)/256;
    scan1_k<<<nb, 256, 0, stream>>>(deg, rp, bsum, NN);
    scan2_k<<<1, 256, 0, stream>>>(bsum, nb);
    scan3_k<<<nb, 256, 0, stream>>>(rp, bsum, NN);
    fill_k<<<(EE+255)/256, 256, 0, stream>>>(dst, src, rp, cursor, srcs);

    const int gN = (NN + 63) / 64;   // 782 blocks
    const int gA = (NN + 3) / 4;     // 12500 blocks

    // ---- h0 = x @ wxW + wxb -> muB ----
    rgemm_k<EPI_BF,4,2,IN_D,float><<<gN, 256, 0, stream>>>(
        x, nullptr, wxP, wxb, nullptr, nullptr, nullptr, muB, nullptr, nullptr, NN);

    // ---- GAT layers ----
    const u16* hin = muB;
    for (int i = 0; i < DEPTH; ++i) {
        rgemm_k<EPI_ZEL,4,2,HH,u16><<<gN, 256, 0, stream>>>(
            hin, nullptr, gatP + i*16384, attl + i*HH, attr + i*HH, nullptr, nullptr,
            zB, el, er, NN);
        attn_k<<<gA, 256, 0, stream>>>(el, er, srcs, rp, deg, alpha);
        agg_k<<<gA, 256, 0, stream>>>(zB, alpha, srcs, rp, deg, gatb + i*HH, coll[i]);
        hin = coll[i];
    }

    // ---- depth: fused 4-gate + c/mu update ----
    rgemm_k<EPI_GATES_FIRST,8,4,2*HH,u16><<<gN, 512, 0, stream>>>(
        coll[0], muB, gateP, igb, stb, fgb, ogb, muB, cbuf, nullptr, NN);
    for (int i = 1; i < DEPTH; ++i)
        rgemm_k<EPI_GATES,8,4,2*HH,u16><<<gN, 512, 0, stream>>>(
            coll[i], muB, gateP + i*131072, igb + i*HH, stb + i*HH, fgb + i*HH, ogb + i*HH,
            muB, cbuf, nullptr, NN);

    // ---- out = relu(mu @ outW + outb) -> f32 ----
    rgemm_k<EPI_RELU,4,1,HH,u16><<<gN, 256, 0, stream>>>(
        muB, nullptr, outP, outb, nullptr, nullptr, nullptr, (float*)d_out, nullptr, nullptr, NN);
}

// Round 9
// 328.393 us; speedup vs baseline: 2.3382x; 1.3374x over previous
//
#include <hip/hip_runtime.h>
#include <math.h>
#include <type_traits>

#define NN 50000
#define EE 800000
#define IN_D 256
#define HH 128
#define OUT_D 64
#define DEPTH 3
#define BK 512
#define NBK 98    // ceil(NN/BK)

typedef unsigned short u16;
typedef __bf16  bf16x8 __attribute__((ext_vector_type(8)));
typedef short   short8 __attribute__((ext_vector_type(8)));
typedef float   f32x4  __attribute__((ext_vector_type(4)));

__device__ __forceinline__ u16 f2b(float f){
    unsigned u = __float_as_uint(f);
    u += 0x7fff + ((u>>16)&1);            // round-to-nearest-even
    return (u16)(u>>16);
}
__device__ __forceinline__ float b2f(u16 h){ return __uint_as_float(((unsigned)h)<<16); }

#define LOG2E 1.4426950408889634f
#if __has_builtin(__builtin_amdgcn_exp2f)
__device__ __forceinline__ float fexp2(float x){ return __builtin_amdgcn_exp2f(x); }
#else
__device__ __forceinline__ float fexp2(float x){ return exp2f(x); }
#endif
#if __has_builtin(__builtin_amdgcn_rcpf)
__device__ __forceinline__ float frcp(float x){ return __builtin_amdgcn_rcpf(x); }
#else
__device__ __forceinline__ float frcp(float x){ return 1.f/x; }
#endif
__device__ __forceinline__ float sigm(float x){ return frcp(1.f + fexp2(-x*LOG2E)); }
__device__ __forceinline__ float ftanh(float x){
    float ax = fabsf(x);
    float u = fexp2(ax * (-2.f*LOG2E));
    float r = (1.f - u) * frcp(1.f + u);
    return copysignf(r, x);
}

// ================= A-resident register GEMM =================
enum { EPI_BF=0, EPI_RELU=1, EPI_ZEL=2, EPI_GATES_FIRST=3, EPI_GATES=4 };

template<int EPI, int WAVES, int CT, int K, typename TA>
__global__ __launch_bounds__(WAVES*64, 4) void rgemm_k(
    const TA* __restrict__ A1, const u16* __restrict__ A2,
    const u16* __restrict__ Bp,
    const float* __restrict__ b1, const float* __restrict__ b2,
    const float* __restrict__ b3, const float* __restrict__ b4,
    void* __restrict__ Out, float* __restrict__ aux1, float* __restrict__ aux2,
    int Nrows)
{
    constexpr int TH = WAVES*64;
    constexpr int KS = K/32;
    constexpr int M  = WAVES*CT*16;
    constexpr bool GATES = (EPI==EPI_GATES || EPI==EPI_GATES_FIRST);
    __shared__ u16 As[64*K];
    __shared__ float elp[(EPI==EPI_ZEL)?64*WAVES:1];
    __shared__ float erp[(EPI==EPI_ZEL)?64*WAVES:1];

    const int tid = threadIdx.x;
    const int rb  = blockIdx.x*64;

    constexpr int CHUNKS = 64*K/(TH*8);
    #pragma unroll
    for (int c = 0; c < CHUNKS; ++c) {
        int h = (tid + c*TH)*8;
        int row = h / K, kk = h % K;
        int grow = rb + row; if (grow >= Nrows) grow = Nrows-1;
        short8 v;
        if constexpr (std::is_same<TA,float>::value) {
            const float* p = (const float*)A1 + (size_t)grow*K + kk;
            float4 x0 = *(const float4*)p;
            float4 x1 = *(const float4*)(p+4);
            v[0]=(short)f2b(x0.x); v[1]=(short)f2b(x0.y); v[2]=(short)f2b(x0.z); v[3]=(short)f2b(x0.w);
            v[4]=(short)f2b(x1.x); v[5]=(short)f2b(x1.y); v[6]=(short)f2b(x1.z); v[7]=(short)f2b(x1.w);
        } else if constexpr (GATES) {
            const u16* p = (kk < HH) ? ((const u16*)A1 + (size_t)grow*HH + kk)
                                     : (A2 + (size_t)grow*HH + (kk-HH));
            v = *(const short8*)p;
        } else {
            v = *(const short8*)((const u16*)A1 + (size_t)grow*K + kk);
        }
        int byte = row*(K*2) + ((kk*2) ^ ((row&7)<<4));
        *(short8*)((char*)As + byte) = v;
    }
    __syncthreads();

    const int lane = tid & 63, w = tid >> 6;
    const int ml = lane & 15, ksel = lane >> 4;
    f32x4 acc[4][CT] = {};
    #pragma unroll
    for (int ks = 0; ks < KS; ++ks) {
        bf16x8 a[4];
        #pragma unroll
        for (int rt = 0; rt < 4; ++rt) {
            int row = rt*16 + ml;
            int byte = row*(K*2) + (((ks*32 + ksel*8)*2) ^ ((row&7)<<4));
            a[rt] = *(const bf16x8*)((const char*)As + byte);
        }
        #pragma unroll
        for (int j = 0; j < CT; ++j) {
            int ctg = j*WAVES + w;
            bf16x8 b = *(const bf16x8*)(Bp + (((size_t)(ctg*KS + ks))<<9) + lane*8);
            #pragma unroll
            for (int rt = 0; rt < 4; ++rt)
                acc[rt][j] = __builtin_amdgcn_mfma_f32_16x16x32_bf16(a[rt], b, acc[rt][j], 0,0,0);
        }
    }

    if constexpr (EPI==EPI_BF || EPI==EPI_RELU) {
        #pragma unroll
        for (int rt = 0; rt < 4; ++rt)
        #pragma unroll
        for (int r = 0; r < 4; ++r) {
            int row = rb + rt*16 + ksel*4 + r;
            if (row >= Nrows) continue;
            #pragma unroll
            for (int j = 0; j < CT; ++j) {
                int gc = (j*WAVES + w)*16 + ml;
                float vv = acc[rt][j][r] + b1[gc];
                if (EPI==EPI_BF) ((u16*)Out)[(size_t)row*M + gc]   = f2b(vv);
                else             ((float*)Out)[(size_t)row*M + gc] = fmaxf(vv, 0.f);
            }
        }
    } else if constexpr (EPI==EPI_ZEL) {
        float pel[4][4] = {}, per[4][4] = {};
        #pragma unroll
        for (int j = 0; j < CT; ++j) {
            int gc = (j*WAVES + w)*16 + ml;
            float alc = b1[gc], arc = b2[gc];
            #pragma unroll
            for (int rt = 0; rt < 4; ++rt)
            #pragma unroll
            for (int r = 0; r < 4; ++r) {
                int row = rb + rt*16 + ksel*4 + r;
                float vv = acc[rt][j][r];
                if (row < Nrows) ((u16*)Out)[(size_t)row*HH + gc] = f2b(vv);
                pel[rt][r] = fmaf(vv, alc, pel[rt][r]);
                per[rt][r] = fmaf(vv, arc, per[rt][r]);
            }
        }
        #pragma unroll
        for (int msk = 1; msk < 16; msk <<= 1)
            #pragma unroll
            for (int rt = 0; rt < 4; ++rt)
            #pragma unroll
            for (int r = 0; r < 4; ++r) {
                pel[rt][r] += __shfl_xor(pel[rt][r], msk);
                per[rt][r] += __shfl_xor(per[rt][r], msk);
            }
        if (ml == 0) {
            #pragma unroll
            for (int rt = 0; rt < 4; ++rt)
            #pragma unroll
            for (int r = 0; r < 4; ++r) {
                int lr = rt*16 + ksel*4 + r;
                elp[lr*WAVES + w] = pel[rt][r];
                erp[lr*WAVES + w] = per[rt][r];
            }
        }
        __syncthreads();
        if (tid < 64) {
            int row = rb + tid;
            if (row < Nrows) {
                float s1 = 0.f, s2 = 0.f;
                #pragma unroll
                for (int wv = 0; wv < WAVES; ++wv) { s1 += elp[tid*WAVES+wv]; s2 += erp[tid*WAVES+wv]; }
                aux1[row] = s1; aux2[row] = s2;
            }
        }
    } else {
        #pragma unroll
        for (int rt = 0; rt < 4; ++rt)
        #pragma unroll
        for (int r = 0; r < 4; ++r) {
            int row = rb + rt*16 + ksel*4 + r;
            if (row >= Nrows) continue;
            int gcg = w*16 + ml;
            size_t o = (size_t)row*HH + gcg;
            float ig = sigm (acc[rt][0][r] + b1[gcg]);
            float st = ftanh(acc[rt][1][r] + b2[gcg]);
            float fg = sigm (acc[rt][2][r] + b3[gcg]);
            float og = sigm (acc[rt][3][r] + b4[gcg]);
            float P  = ig * st;
            float cn = (EPI==EPI_GATES_FIRST) ? P : fmaf(fg, aux1[o], P);
            aux1[o] = cn;
            ((u16*)Out)[o] = f2b(og * ftanh(cn));
        }
    }
}

// ================= weight pack =================
struct PK  { const float* s; u16* d; int K; int Mc; };
struct PKs { PK t[17]; };
__global__ __launch_bounds__(256) void pack_k(PKs ps){
    const PK t = ps.t[blockIdx.y];
    int o = blockIdx.x*256 + threadIdx.x;
    if (o >= t.K * t.Mc) return;
    int i = o & 7, lane = (o>>3) & 63, rst = o >> 9;
    int KS = t.K >> 5;
    int ks = rst % KS, ct = rst / KS;
    int col = ct*16 + (lane & 15);
    int k   = ks*32 + (lane>>4)*8 + i;
    t.d[o] = f2b(t.s[(size_t)k*t.Mc + col]);
}

// ================= bucketized CSR build =================
__global__ __launch_bounds__(256) void binh_k(const int* __restrict__ dst, int* __restrict__ bcnt){
    __shared__ int h[NBK];
    int t = threadIdx.x;
    if (t < NBK) h[t] = 0;
    __syncthreads();
    int base = blockIdx.x*4096;
    #pragma unroll
    for (int c = 0; c < 16; ++c){ int e = base + c*256 + t; if (e < EE) atomicAdd(&h[dst[e]>>9], 1); }
    __syncthreads();
    if (t < NBK && h[t]) atomicAdd(&bcnt[t], h[t]);
}
__global__ __launch_bounds__(128) void bscan_k(const int* __restrict__ bcnt,
                                               int* __restrict__ bbase, int* __restrict__ gcur){
    __shared__ int s[128];
    int t = threadIdx.x;
    int v = (t < NBK) ? bcnt[t] : 0;
    s[t] = v; __syncthreads();
    for (int off=1; off<128; off<<=1){ int x = (t>=off)? s[t-off] : 0; __syncthreads(); s[t] += x; __syncthreads(); }
    if (t < NBK){ bbase[t] = s[t]-v; gcur[t] = s[t]-v; }
}
__global__ __launch_bounds__(256) void binsc_k(const int* __restrict__ dst, const int* __restrict__ src,
                                               int* __restrict__ gcur, unsigned* __restrict__ staged){
    __shared__ int h[NBK], bb[NBK], lc[NBK];
    int t = threadIdx.x;
    if (t < NBK){ h[t]=0; lc[t]=0; }
    __syncthreads();
    int base = blockIdx.x*4096;
    int d[16], s[16];
    #pragma unroll
    for (int c = 0; c < 16; ++c){
        int e = base + c*256 + t; d[c] = -1;
        if (e < EE){ d[c] = dst[e]; s[c] = src[e]; atomicAdd(&h[d[c]>>9], 1); }
    }
    __syncthreads();
    if (t < NBK && h[t]) bb[t] = atomicAdd(&gcur[t], h[t]);
    __syncthreads();
    #pragma unroll
    for (int c = 0; c < 16; ++c) if (d[c] >= 0){
        int b = d[c]>>9;
        int r = atomicAdd(&lc[b], 1);
        staged[bb[b] + r] = ((unsigned)(d[c] & 511) << 16) | (unsigned)s[c];
    }
}
__global__ __launch_bounds__(BK) void build_k(const int* __restrict__ bcnt, const int* __restrict__ bbase,
                                              const unsigned* __restrict__ staged,
                                              int* __restrict__ rp, int* __restrict__ deg, u16* __restrict__ srcs){
    __shared__ int soff[BK], cur[BK];
    int t = threadIdx.x, bk = blockIdx.x;
    int n0 = bk*BK;
    soff[t] = 0; cur[t] = 0;
    __syncthreads();
    int cb = bcnt[bk], eb = bbase[bk];
    for (int j = t; j < cb; j += BK) atomicAdd(&soff[staged[eb+j]>>16], 1);
    __syncthreads();
    int d0 = soff[t];
    for (int off=1; off<BK; off<<=1){ int x = (t>=off)? soff[t-off] : 0; __syncthreads(); soff[t] += x; __syncthreads(); }
    int ex = soff[t] - d0;
    __syncthreads();
    soff[t] = ex;
    int n = n0 + t;
    if (n < NN){ deg[n] = d0; rp[n] = eb + ex; }
    __syncthreads();
    for (int j = t; j < cb; j += BK){
        unsigned p = staged[eb+j];
        int l = p >> 16;
        int r = atomicAdd(&cur[l], 1);
        srcs[eb + soff[l] + r] = (u16)(p & 0xffff);
    }
}

// ================= fused attention-softmax + gather =================
// Gather loop has a WAVE-UNIFORM trip count (cntp = round-up-8(cnt)): every lane
// executes the same iterations, so all __shfl sources are active lanes (the R8
// bug was divergent-exit slots making shfl read inactive lanes -> undefined).
// Out-of-range slots contribute weight 0 (a_reg=0 for lane>=cnt) and gather z[0].
__global__ __launch_bounds__(256) void gat_k(
    const u16* __restrict__ z, const float* __restrict__ el, const float* __restrict__ er,
    const u16* __restrict__ srcs, const int* __restrict__ rp, const int* __restrict__ deg,
    const float* __restrict__ bias, u16* __restrict__ hout)
{
    int n = blockIdx.x*4 + (threadIdx.x>>6);
    if (n >= NN) return;
    int lane = threadIdx.x & 63;
    int start = rp[n], cnt = deg[n];
    float ern = er[n];
    const int slot = lane >> 4;
    const int ch   = (lane & 15) * 8;
    float acc[8] = {};

    if (cnt <= 64) {
        float v = -1e30f; int s_reg = 0;
        if (lane < cnt) {
            s_reg = srcs[start + lane];
            float tv = el[s_reg] + ern;
            v = tv >= 0.f ? tv : 0.2f*tv;
        }
        float m = v;
        #pragma unroll
        for (int off=1; off<64; off<<=1) m = fmaxf(m, __shfl_xor(m, off));
        float a = (lane < cnt) ? fexp2((v - m)*LOG2E) : 0.f;
        float ss = a;
        #pragma unroll
        for (int off=1; off<64; off<<=1) ss += __shfl_xor(ss, off);
        float a_reg = a * frcp(fmaxf(ss, 1e-16f));

        const int cntp = (cnt + 7) & ~7;    // uniform across the wave
        for (int i = slot; i < cntp; i += 8) {
            float w0 = __shfl(a_reg, i),   w1 = __shfl(a_reg, i+4);
            int   s0 = __shfl(s_reg, i),   s1 = __shfl(s_reg, i+4);
            short8 v0 = *(const short8*)(z + (size_t)s0*HH + ch);
            short8 v1 = *(const short8*)(z + (size_t)s1*HH + ch);
            #pragma unroll
            for (int j=0;j<8;j++) acc[j] = fmaf(w1, b2f((u16)v1[j]), fmaf(w0, b2f((u16)v0[j]), acc[j]));
        }
    } else {   // generic fallback (degree > 64: not expected for this graph; no shfl in divergent loops)
        float m = -1e30f;
        for (int i=lane; i<cnt; i+=64){ float tv = el[srcs[start+i]] + ern; tv = tv>=0.f?tv:0.2f*tv; m = fmaxf(m, tv); }
        #pragma unroll
        for (int off=1; off<64; off<<=1) m = fmaxf(m, __shfl_xor(m, off));
        float ss = 0.f;
        for (int i=lane; i<cnt; i+=64){ float tv = el[srcs[start+i]] + ern; tv = tv>=0.f?tv:0.2f*tv; ss += fexp2((tv-m)*LOG2E); }
        #pragma unroll
        for (int off=1; off<64; off<<=1) ss += __shfl_xor(ss, off);
        float inv = frcp(fmaxf(ss, 1e-16f));
        for (int i=slot; i<cnt; i+=4) {
            int sn = srcs[start+i];
            float tv = el[sn] + ern; tv = tv>=0.f?tv:0.2f*tv;
            float w0 = fexp2((tv-m)*LOG2E) * inv;
            short8 v0 = *(const short8*)(z + (size_t)sn*HH + ch);
            #pragma unroll
            for (int j=0;j<8;j++) acc[j] = fmaf(w0, b2f((u16)v0[j]), acc[j]);
        }
    }
    #pragma unroll
    for (int j=0;j<8;j++){ acc[j] += __shfl_xor(acc[j],16); acc[j] += __shfl_xor(acc[j],32); }
    if (slot == 0) {
        short8 o8;
        #pragma unroll
        for (int j=0;j<8;j++) o8[j] = (short)f2b(ftanh(acc[j] + bias[ch+j]));
        *(short8*)(hout + (size_t)n*HH + ch) = o8;
    }
}

extern "C" void kernel_launch(void* const* d_in, const int* in_sizes, int n_in,
                              void* d_out, int out_size, void* d_ws, size_t ws_size,
                              hipStream_t stream)
{
    const float* x    = (const float*)d_in[0];
    const int*   src  = (const int*)d_in[1];
    const int*   dst  = (const int*)d_in[2];
    const float* wxW  = (const float*)d_in[3];
    const float* wxb  = (const float*)d_in[4];
    const float* gatW = (const float*)d_in[5];
    const float* gatb = (const float*)d_in[6];
    const float* attl = (const float*)d_in[7];
    const float* attr = (const float*)d_in[8];
    const float* igW  = (const float*)d_in[9];
    const float* igb  = (const float*)d_in[10];
    const float* fgW  = (const float*)d_in[11];
    const float* fgb  = (const float*)d_in[12];
    const float* ogW  = (const float*)d_in[13];
    const float* ogb  = (const float*)d_in[14];
    const float* stW  = (const float*)d_in[15];
    const float* stb  = (const float*)d_in[16];
    const float* outW = (const float*)d_in[17];
    const float* outb = (const float*)d_in[18];

    char* w = (char*)d_ws;
    auto alloc = [&](size_t bytes)->char* { char* p = w; w += (bytes + 255) & ~(size_t)255; return p; };
    const size_t NH = (size_t)NN * HH;
    u16*      muB    = (u16*)alloc(NH*2);
    u16*      zB     = (u16*)alloc(NH*2);
    u16*      coll0  = (u16*)alloc(NH*2);
    u16*      coll1  = (u16*)alloc(NH*2);
    u16*      coll2  = (u16*)alloc(NH*2);
    float*    cbuf   = (float*)alloc(NH*4);
    float*    el     = (float*)alloc((size_t)NN*4);
    float*    er     = (float*)alloc((size_t)NN*4);
    unsigned* staged = (unsigned*)alloc((size_t)EE*4);
    u16*      srcs   = (u16*)alloc((size_t)EE*2);
    int*      deg    = (int*)alloc((size_t)NN*4);
    int*      rp     = (int*)alloc((size_t)NN*4);
    int*      bcnt   = (int*)alloc(128*4);
    int*      bbase  = (int*)alloc(128*4);
    int*      gcur   = (int*)alloc(128*4);
    u16*      bpool  = (u16*)alloc(483328*2);
    u16* wxP   = bpool;
    u16* gatP  = bpool + 32768;
    u16* gateP = bpool + 81920;
    u16* outP  = bpool + 475136;
    u16* coll[3] = {coll0, coll1, coll2};

    // ---- pack weights into MFMA fragment order ----
    PKs ps;
    ps.t[0] = {wxW, wxP, IN_D, HH};
    for (int i=0;i<3;i++) ps.t[1+i]  = {gatW + (size_t)i*HH*HH,   gatP  + i*16384,           HH,   HH};
    for (int i=0;i<3;i++) ps.t[4+i]  = {igW  + (size_t)i*2*HH*HH, gateP + i*131072,          2*HH, HH};
    for (int i=0;i<3;i++) ps.t[7+i]  = {stW  + (size_t)i*2*HH*HH, gateP + i*131072 + 32768,  2*HH, HH};
    for (int i=0;i<3;i++) ps.t[10+i] = {fgW  + (size_t)i*2*HH*HH, gateP + i*131072 + 65536,  2*HH, HH};
    for (int i=0;i<3;i++) ps.t[13+i] = {ogW  + (size_t)i*2*HH*HH, gateP + i*131072 + 98304,  2*HH, HH};
    ps.t[16] = {outW, outP, HH, OUT_D};
    pack_k<<<dim3(128,17), 256, 0, stream>>>(ps);

    // ---- bucketized CSR build ----
    hipMemsetAsync(bcnt, 0, 128*4, stream);
    const int gE = (EE + 4095) / 4096;   // 196
    binh_k <<<gE, 256, 0, stream>>>(dst, bcnt);
    bscan_k<<<1, 128, 0, stream>>>(bcnt, bbase, gcur);
    binsc_k<<<gE, 256, 0, stream>>>(dst, src, gcur, staged);
    build_k<<<NBK, BK, 0, stream>>>(bcnt, bbase, staged, rp, deg, srcs);

    const int gN = (NN + 63) / 64;   // 782
    const int gA = (NN + 3) / 4;     // 12500

    // ---- h0 = x @ wxW + wxb -> muB ----
    rgemm_k<EPI_BF,4,2,IN_D,float><<<gN, 256, 0, stream>>>(
        x, nullptr, wxP, wxb, nullptr, nullptr, nullptr, muB, nullptr, nullptr, NN);

    // ---- GAT layers ----
    const u16* hin = muB;
    for (int i = 0; i < DEPTH; ++i) {
        rgemm_k<EPI_ZEL,4,2,HH,u16><<<gN, 256, 0, stream>>>(
            hin, nullptr, gatP + i*16384, attl + i*HH, attr + i*HH, nullptr, nullptr,
            zB, el, er, NN);
        gat_k<<<gA, 256, 0, stream>>>(zB, el, er, srcs, rp, deg, gatb + i*HH, coll[i]);
        hin = coll[i];
    }

    // ---- depth: fused 4-gate + c/mu update ----
    rgemm_k<EPI_GATES_FIRST,8,4,2*HH,u16><<<gN, 512, 0, stream>>>(
        coll[0], muB, gateP, igb, stb, fgb, ogb, muB, cbuf, nullptr, NN);
    for (int i = 1; i < DEPTH; ++i)
        rgemm_k<EPI_GATES,8,4,2*HH,u16><<<gN, 512, 0, stream>>>(
            coll[i], muB, gateP + i*131072, igb + i*HH, stb + i*HH, fgb + i*HH, ogb + i*HH,
            muB, cbuf, nullptr, NN);

    // ---- out = relu(mu @ outW + outb) -> f32 ----
    rgemm_k<EPI_RELU,4,1,HH,u16><<<gN, 256, 0, stream>>>(
        muB, nullptr, outP, outb, nullptr, nullptr, nullptr, (float*)d_out, nullptr, nullptr, NN);
}

// Round 10
// 320.952 us; speedup vs baseline: 2.3925x; 1.0232x over previous
//
#include <hip/hip_runtime.h>
#include <math.h>
#include <type_traits>

#define NN 50000
#define EE 800000
#define IN_D 256
#define HH 128
#define OUT_D 64
#define DEPTH 3
#define BK 512
#define NBK 98    // ceil(NN/BK)

typedef unsigned short u16;
typedef __bf16  bf16x8 __attribute__((ext_vector_type(8)));
typedef short   short8 __attribute__((ext_vector_type(8)));
typedef float   f32x4  __attribute__((ext_vector_type(4)));

__device__ __forceinline__ u16 f2b(float f){
    unsigned u = __float_as_uint(f);
    u += 0x7fff + ((u>>16)&1);            // round-to-nearest-even
    return (u16)(u>>16);
}
__device__ __forceinline__ float b2f(u16 h){ return __uint_as_float(((unsigned)h)<<16); }

#define LOG2E 1.4426950408889634f
#if __has_builtin(__builtin_amdgcn_exp2f)
__device__ __forceinline__ float fexp2(float x){ return __builtin_amdgcn_exp2f(x); }
#else
__device__ __forceinline__ float fexp2(float x){ return exp2f(x); }
#endif
#if __has_builtin(__builtin_amdgcn_rcpf)
__device__ __forceinline__ float frcp(float x){ return __builtin_amdgcn_rcpf(x); }
#else
__device__ __forceinline__ float frcp(float x){ return 1.f/x; }
#endif
__device__ __forceinline__ float sigm(float x){ return frcp(1.f + fexp2(-x*LOG2E)); }
__device__ __forceinline__ float ftanh(float x){
    float ax = fabsf(x);
    float u = fexp2(ax * (-2.f*LOG2E));
    float r = (1.f - u) * frcp(1.f + u);
    return copysignf(r, x);
}

// ================= A-resident register GEMM (h0 / zel / out) =================
enum { EPI_BF=0, EPI_RELU=1, EPI_ZEL=2 };

template<int EPI, int WAVES, int CT, int K, typename TA>
__global__ __launch_bounds__(WAVES*64, 4) void rgemm_k(
    const TA* __restrict__ A1,
    const u16* __restrict__ Bp,
    const float* __restrict__ b1, const float* __restrict__ b2,
    void* __restrict__ Out, float* __restrict__ aux1, float* __restrict__ aux2,
    int Nrows)
{
    constexpr int TH = WAVES*64;
    constexpr int KS = K/32;
    constexpr int M  = WAVES*CT*16;
    __shared__ u16 As[64*K];
    __shared__ float elp[(EPI==EPI_ZEL)?64*WAVES:1];
    __shared__ float erp[(EPI==EPI_ZEL)?64*WAVES:1];

    const int tid = threadIdx.x;
    const int rb  = blockIdx.x*64;

    constexpr int CHUNKS = 64*K/(TH*8);
    #pragma unroll
    for (int c = 0; c < CHUNKS; ++c) {
        int h = (tid + c*TH)*8;
        int row = h / K, kk = h % K;
        int grow = rb + row; if (grow >= Nrows) grow = Nrows-1;
        short8 v;
        if constexpr (std::is_same<TA,float>::value) {
            const float* p = (const float*)A1 + (size_t)grow*K + kk;
            float4 x0 = *(const float4*)p;
            float4 x1 = *(const float4*)(p+4);
            v[0]=(short)f2b(x0.x); v[1]=(short)f2b(x0.y); v[2]=(short)f2b(x0.z); v[3]=(short)f2b(x0.w);
            v[4]=(short)f2b(x1.x); v[5]=(short)f2b(x1.y); v[6]=(short)f2b(x1.z); v[7]=(short)f2b(x1.w);
        } else {
            v = *(const short8*)((const u16*)A1 + (size_t)grow*K + kk);
        }
        int byte = row*(K*2) + ((kk*2) ^ ((row&7)<<4));
        *(short8*)((char*)As + byte) = v;
    }
    __syncthreads();

    const int lane = tid & 63, w = tid >> 6;
    const int ml = lane & 15, ksel = lane >> 4;
    f32x4 acc[4][CT] = {};
    #pragma unroll
    for (int ks = 0; ks < KS; ++ks) {
        bf16x8 a[4];
        #pragma unroll
        for (int rt = 0; rt < 4; ++rt) {
            int row = rt*16 + ml;
            int byte = row*(K*2) + (((ks*32 + ksel*8)*2) ^ ((row&7)<<4));
            a[rt] = *(const bf16x8*)((const char*)As + byte);
        }
        #pragma unroll
        for (int j = 0; j < CT; ++j) {
            int ctg = j*WAVES + w;
            bf16x8 b = *(const bf16x8*)(Bp + (((size_t)(ctg*KS + ks))<<9) + lane*8);
            #pragma unroll
            for (int rt = 0; rt < 4; ++rt)
                acc[rt][j] = __builtin_amdgcn_mfma_f32_16x16x32_bf16(a[rt], b, acc[rt][j], 0,0,0);
        }
    }

    if constexpr (EPI==EPI_BF || EPI==EPI_RELU) {
        #pragma unroll
        for (int rt = 0; rt < 4; ++rt)
        #pragma unroll
        for (int r = 0; r < 4; ++r) {
            int row = rb + rt*16 + ksel*4 + r;
            if (row >= Nrows) continue;
            #pragma unroll
            for (int j = 0; j < CT; ++j) {
                int gc = (j*WAVES + w)*16 + ml;
                float vv = acc[rt][j][r] + b1[gc];
                if (EPI==EPI_BF) ((u16*)Out)[(size_t)row*M + gc]   = f2b(vv);
                else             ((float*)Out)[(size_t)row*M + gc] = fmaxf(vv, 0.f);
            }
        }
    } else {   // EPI_ZEL
        float pel[4][4] = {}, per[4][4] = {};
        #pragma unroll
        for (int j = 0; j < CT; ++j) {
            int gc = (j*WAVES + w)*16 + ml;
            float alc = b1[gc], arc = b2[gc];
            #pragma unroll
            for (int rt = 0; rt < 4; ++rt)
            #pragma unroll
            for (int r = 0; r < 4; ++r) {
                int row = rb + rt*16 + ksel*4 + r;
                float vv = acc[rt][j][r];
                if (row < Nrows) ((u16*)Out)[(size_t)row*HH + gc] = f2b(vv);
                pel[rt][r] = fmaf(vv, alc, pel[rt][r]);
                per[rt][r] = fmaf(vv, arc, per[rt][r]);
            }
        }
        #pragma unroll
        for (int msk = 1; msk < 16; msk <<= 1)
            #pragma unroll
            for (int rt = 0; rt < 4; ++rt)
            #pragma unroll
            for (int r = 0; r < 4; ++r) {
                pel[rt][r] += __shfl_xor(pel[rt][r], msk);
                per[rt][r] += __shfl_xor(per[rt][r], msk);
            }
        if (ml == 0) {
            #pragma unroll
            for (int rt = 0; rt < 4; ++rt)
            #pragma unroll
            for (int r = 0; r < 4; ++r) {
                int lr = rt*16 + ksel*4 + r;
                elp[lr*WAVES + w] = pel[rt][r];
                erp[lr*WAVES + w] = per[rt][r];
            }
        }
        __syncthreads();
        if (tid < 64) {
            int row = rb + tid;
            if (row < Nrows) {
                float s1 = 0.f, s2 = 0.f;
                #pragma unroll
                for (int wv = 0; wv < WAVES; ++wv) { s1 += elp[tid*WAVES+wv]; s2 += erp[tid*WAVES+wv]; }
                aux1[row] = s1; aux2[row] = s2;
            }
        }
    }
}

// ================= fused 3-layer depth kernel =================
// Block owns 64 rows for the whole depth phase. mu lives in a swizzled LDS tile,
// c lives in registers (each wave owns h-cols w*16..w*16+15 across all 4 gates,
// so c/mu updates are thread-local). Per layer: stage coll_i -> As, K=256 MFMA
// loop over [As | Ms], gate math in registers, mu -> Ms. No cbuf traffic at all.
__global__ __launch_bounds__(512, 4) void depth_k(
    const u16* __restrict__ coll0, const u16* __restrict__ coll1, const u16* __restrict__ coll2,
    u16* __restrict__ mu,
    const u16* __restrict__ gateP,
    const float* __restrict__ igb, const float* __restrict__ stb,
    const float* __restrict__ fgb, const float* __restrict__ ogb,
    int Nrows)
{
    __shared__ u16 As[64*HH];   // coll tile (swizzled), 16KB
    __shared__ u16 Ms[64*HH];   // mu tile  (swizzled), 16KB
    const int tid = threadIdx.x;
    const int rb  = blockIdx.x*64;
    const int lane = tid & 63, w = tid >> 6;
    const int ml = lane & 15, ksel = lane >> 4;
    const int gcg = w*16 + ml;

    // stage initial mu (= h0)
    #pragma unroll
    for (int c = 0; c < 2; ++c) {
        int h = (tid + c*512)*8;
        int row = h >> 7, kk = h & 127;
        int grow = rb + row; if (grow >= Nrows) grow = Nrows-1;
        short8 v = *(const short8*)(mu + (size_t)grow*HH + kk);
        *(short8*)((char*)Ms + row*256 + ((kk*2) ^ ((row&7)<<4))) = v;
    }

    float cc[4][4];
    const u16* colls[3] = {coll0, coll1, coll2};

    for (int i = 0; i < DEPTH; ++i) {
        const u16* coll = colls[i];
        #pragma unroll
        for (int c = 0; c < 2; ++c) {
            int h = (tid + c*512)*8;
            int row = h >> 7, kk = h & 127;
            int grow = rb + row; if (grow >= Nrows) grow = Nrows-1;
            short8 v = *(const short8*)(coll + (size_t)grow*HH + kk);
            *(short8*)((char*)As + row*256 + ((kk*2) ^ ((row&7)<<4))) = v;
        }
        __syncthreads();

        f32x4 acc[4][4] = {};   // [rt][gate]
        #pragma unroll
        for (int ks = 0; ks < 8; ++ks) {
            const char* Sb = (ks < 4) ? (const char*)As : (const char*)Ms;
            int kk2 = ((ks & 3)*32 + ksel*8)*2;
            bf16x8 a[4];
            #pragma unroll
            for (int rt = 0; rt < 4; ++rt) {
                int row = rt*16 + ml;
                a[rt] = *(const bf16x8*)(Sb + row*256 + (kk2 ^ ((row&7)<<4)));
            }
            #pragma unroll
            for (int j = 0; j < 4; ++j) {
                bf16x8 b = *(const bf16x8*)(gateP + (size_t)i*131072 + (j*8 + w)*4096 + ks*512 + lane*8);
                #pragma unroll
                for (int rt = 0; rt < 4; ++rt)
                    acc[rt][j] = __builtin_amdgcn_mfma_f32_16x16x32_bf16(a[rt], b, acc[rt][j], 0,0,0);
            }
        }
        __syncthreads();   // all Ms reads done before overwrite

        float bi = igb[i*HH + gcg], bs = stb[i*HH + gcg];
        float bf_ = fgb[i*HH + gcg], bo = ogb[i*HH + gcg];
        #pragma unroll
        for (int rt = 0; rt < 4; ++rt)
        #pragma unroll
        for (int r = 0; r < 4; ++r) {
            float ig = sigm (acc[rt][0][r] + bi);
            float st = ftanh(acc[rt][1][r] + bs);
            float fg = sigm (acc[rt][2][r] + bf_);
            float og = sigm (acc[rt][3][r] + bo);
            float P  = ig * st;
            float cn = (i == 0) ? P : fmaf(fg, cc[rt][r], P);
            cc[rt][r] = cn;
            float mun = og * ftanh(cn);
            int lrow = rt*16 + ksel*4 + r;
            *(u16*)((char*)Ms + lrow*256 + ((gcg*2) ^ ((lrow&7)<<4))) = f2b(mun);
        }
        __syncthreads();   // Ms writes visible; As safe to restage
    }

    // final mu write-back
    #pragma unroll
    for (int c = 0; c < 2; ++c) {
        int h = (tid + c*512)*8;
        int row = h >> 7, kk = h & 127;
        int grow = rb + row;
        if (grow < Nrows) {
            short8 v = *(const short8*)((const char*)Ms + row*256 + ((kk*2) ^ ((row&7)<<4)));
            *(short8*)(mu + (size_t)grow*HH + kk) = v;
        }
    }
}

// ================= weight pack =================
struct PK  { const float* s; u16* d; int K; int Mc; };
struct PKs { PK t[17]; };
__global__ __launch_bounds__(256) void pack_k(PKs ps){
    const PK t = ps.t[blockIdx.y];
    int o = blockIdx.x*256 + threadIdx.x;
    if (o >= t.K * t.Mc) return;
    int i = o & 7, lane = (o>>3) & 63, rst = o >> 9;
    int KS = t.K >> 5;
    int ks = rst % KS, ct = rst / KS;
    int col = ct*16 + (lane & 15);
    int k   = ks*32 + (lane>>4)*8 + i;
    t.d[o] = f2b(t.s[(size_t)k*t.Mc + col]);
}

// ================= bucketized CSR build =================
__global__ __launch_bounds__(256) void binh_k(const int* __restrict__ dst, int* __restrict__ bcnt){
    __shared__ int h[NBK];
    int t = threadIdx.x;
    if (t < NBK) h[t] = 0;
    __syncthreads();
    int base = blockIdx.x*4096;
    #pragma unroll
    for (int c = 0; c < 16; ++c){ int e = base + c*256 + t; if (e < EE) atomicAdd(&h[dst[e]>>9], 1); }
    __syncthreads();
    if (t < NBK && h[t]) atomicAdd(&bcnt[t], h[t]);
}
__global__ __launch_bounds__(128) void bscan_k(const int* __restrict__ bcnt,
                                               int* __restrict__ bbase, int* __restrict__ gcur){
    __shared__ int s[128];
    int t = threadIdx.x;
    int v = (t < NBK) ? bcnt[t] : 0;
    s[t] = v; __syncthreads();
    for (int off=1; off<128; off<<=1){ int x = (t>=off)? s[t-off] : 0; __syncthreads(); s[t] += x; __syncthreads(); }
    if (t < NBK){ bbase[t] = s[t]-v; gcur[t] = s[t]-v; }
}
__global__ __launch_bounds__(256) void binsc_k(const int* __restrict__ dst, const int* __restrict__ src,
                                               int* __restrict__ gcur, unsigned* __restrict__ staged){
    __shared__ int h[NBK], bb[NBK], lc[NBK];
    int t = threadIdx.x;
    if (t < NBK){ h[t]=0; lc[t]=0; }
    __syncthreads();
    int base = blockIdx.x*4096;
    int d[16], s[16];
    #pragma unroll
    for (int c = 0; c < 16; ++c){
        int e = base + c*256 + t; d[c] = -1;
        if (e < EE){ d[c] = dst[e]; s[c] = src[e]; atomicAdd(&h[d[c]>>9], 1); }
    }
    __syncthreads();
    if (t < NBK && h[t]) bb[t] = atomicAdd(&gcur[t], h[t]);
    __syncthreads();
    #pragma unroll
    for (int c = 0; c < 16; ++c) if (d[c] >= 0){
        int b = d[c]>>9;
        int r = atomicAdd(&lc[b], 1);
        staged[bb[b] + r] = ((unsigned)(d[c] & 511) << 16) | (unsigned)s[c];
    }
}
__global__ __launch_bounds__(BK) void build_k(const int* __restrict__ bcnt, const int* __restrict__ bbase,
                                              const unsigned* __restrict__ staged,
                                              int* __restrict__ rp, int* __restrict__ deg, u16* __restrict__ srcs){
    __shared__ int soff[BK], cur[BK];
    int t = threadIdx.x, bk = blockIdx.x;
    int n0 = bk*BK;
    soff[t] = 0; cur[t] = 0;
    __syncthreads();
    int cb = bcnt[bk], eb = bbase[bk];
    for (int j = t; j < cb; j += BK) atomicAdd(&soff[staged[eb+j]>>16], 1);
    __syncthreads();
    int d0 = soff[t];
    for (int off=1; off<BK; off<<=1){ int x = (t>=off)? soff[t-off] : 0; __syncthreads(); soff[t] += x; __syncthreads(); }
    int ex = soff[t] - d0;
    __syncthreads();
    soff[t] = ex;
    int n = n0 + t;
    if (n < NN){ deg[n] = d0; rp[n] = eb + ex; }
    __syncthreads();
    for (int j = t; j < cb; j += BK){
        unsigned p = staged[eb+j];
        int l = p >> 16;
        int r = atomicAdd(&cur[l], 1);
        srcs[eb + soff[l] + r] = (u16)(p & 0xffff);
    }
}

// ================= fused attention-softmax + gather =================
// Wave-uniform gather trip count: all lanes execute the same iterations so every
// __shfl source lane is active (R8 lesson). OOB slots: weight 0, gather z[0].
__global__ __launch_bounds__(256) void gat_k(
    const u16* __restrict__ z, const float* __restrict__ el, const float* __restrict__ er,
    const u16* __restrict__ srcs, const int* __restrict__ rp, const int* __restrict__ deg,
    const float* __restrict__ bias, u16* __restrict__ hout)
{
    int n = blockIdx.x*4 + (threadIdx.x>>6);
    if (n >= NN) return;
    int lane = threadIdx.x & 63;
    int start = rp[n], cnt = deg[n];
    float ern = er[n];
    const int slot = lane >> 4;
    const int ch   = (lane & 15) * 8;
    float acc[8] = {};

    if (cnt <= 64) {
        float v = -1e30f; int s_reg = 0;
        if (lane < cnt) {
            s_reg = srcs[start + lane];
            float tv = el[s_reg] + ern;
            v = tv >= 0.f ? tv : 0.2f*tv;
        }
        float m = v;
        #pragma unroll
        for (int off=1; off<64; off<<=1) m = fmaxf(m, __shfl_xor(m, off));
        float a = (lane < cnt) ? fexp2((v - m)*LOG2E) : 0.f;
        float ss = a;
        #pragma unroll
        for (int off=1; off<64; off<<=1) ss += __shfl_xor(ss, off);
        float a_reg = a * frcp(fmaxf(ss, 1e-16f));

        const int cntp = (cnt + 7) & ~7;
        for (int i = slot; i < cntp; i += 8) {
            float w0 = __shfl(a_reg, i),   w1 = __shfl(a_reg, i+4);
            int   s0 = __shfl(s_reg, i),   s1 = __shfl(s_reg, i+4);
            short8 v0 = *(const short8*)(z + (size_t)s0*HH + ch);
            short8 v1 = *(const short8*)(z + (size_t)s1*HH + ch);
            #pragma unroll
            for (int j=0;j<8;j++) acc[j] = fmaf(w1, b2f((u16)v1[j]), fmaf(w0, b2f((u16)v0[j]), acc[j]));
        }
    } else {
        float m = -1e30f;
        for (int i=lane; i<cnt; i+=64){ float tv = el[srcs[start+i]] + ern; tv = tv>=0.f?tv:0.2f*tv; m = fmaxf(m, tv); }
        #pragma unroll
        for (int off=1; off<64; off<<=1) m = fmaxf(m, __shfl_xor(m, off));
        float ss = 0.f;
        for (int i=lane; i<cnt; i+=64){ float tv = el[srcs[start+i]] + ern; tv = tv>=0.f?tv:0.2f*tv; ss += fexp2((tv-m)*LOG2E); }
        #pragma unroll
        for (int off=1; off<64; off<<=1) ss += __shfl_xor(ss, off);
        float inv = frcp(fmaxf(ss, 1e-16f));
        for (int i=slot; i<cnt; i+=4) {
            int sn = srcs[start+i];
            float tv = el[sn] + ern; tv = tv>=0.f?tv:0.2f*tv;
            float w0 = fexp2((tv-m)*LOG2E) * inv;
            short8 v0 = *(const short8*)(z + (size_t)sn*HH + ch);
            #pragma unroll
            for (int j=0;j<8;j++) acc[j] = fmaf(w0, b2f((u16)v0[j]), acc[j]);
        }
    }
    #pragma unroll
    for (int j=0;j<8;j++){ acc[j] += __shfl_xor(acc[j],16); acc[j] += __shfl_xor(acc[j],32); }
    if (slot == 0) {
        short8 o8;
        #pragma unroll
        for (int j=0;j<8;j++) o8[j] = (short)f2b(ftanh(acc[j] + bias[ch+j]));
        *(short8*)(hout + (size_t)n*HH + ch) = o8;
    }
}

extern "C" void kernel_launch(void* const* d_in, const int* in_sizes, int n_in,
                              void* d_out, int out_size, void* d_ws, size_t ws_size,
                              hipStream_t stream)
{
    const float* x    = (const float*)d_in[0];
    const int*   src  = (const int*)d_in[1];
    const int*   dst  = (const int*)d_in[2];
    const float* wxW  = (const float*)d_in[3];
    const float* wxb  = (const float*)d_in[4];
    const float* gatW = (const float*)d_in[5];
    const float* gatb = (const float*)d_in[6];
    const float* attl = (const float*)d_in[7];
    const float* attr = (const float*)d_in[8];
    const float* igW  = (const float*)d_in[9];
    const float* igb  = (const float*)d_in[10];
    const float* fgW  = (const float*)d_in[11];
    const float* fgb  = (const float*)d_in[12];
    const float* ogW  = (const float*)d_in[13];
    const float* ogb  = (const float*)d_in[14];
    const float* stW  = (const float*)d_in[15];
    const float* stb  = (const float*)d_in[16];
    const float* outW = (const float*)d_in[17];
    const float* outb = (const float*)d_in[18];

    char* w = (char*)d_ws;
    auto alloc = [&](size_t bytes)->char* { char* p = w; w += (bytes + 255) & ~(size_t)255; return p; };
    const size_t NH = (size_t)NN * HH;
    u16*      muB    = (u16*)alloc(NH*2);
    u16*      zB     = (u16*)alloc(NH*2);
    u16*      coll0  = (u16*)alloc(NH*2);
    u16*      coll1  = (u16*)alloc(NH*2);
    u16*      coll2  = (u16*)alloc(NH*2);
    float*    el     = (float*)alloc((size_t)NN*4);
    float*    er     = (float*)alloc((size_t)NN*4);
    unsigned* staged = (unsigned*)alloc((size_t)EE*4);
    u16*      srcs   = (u16*)alloc((size_t)EE*2);
    int*      deg    = (int*)alloc((size_t)NN*4);
    int*      rp     = (int*)alloc((size_t)NN*4);
    int*      bcnt   = (int*)alloc(128*4);
    int*      bbase  = (int*)alloc(128*4);
    int*      gcur   = (int*)alloc(128*4);
    u16*      bpool  = (u16*)alloc(483328*2);
    u16* wxP   = bpool;
    u16* gatP  = bpool + 32768;
    u16* gateP = bpool + 81920;
    u16* outP  = bpool + 475136;
    u16* coll[3] = {coll0, coll1, coll2};

    // ---- pack weights into MFMA fragment order ----
    PKs ps;
    ps.t[0] = {wxW, wxP, IN_D, HH};
    for (int i=0;i<3;i++) ps.t[1+i]  = {gatW + (size_t)i*HH*HH,   gatP  + i*16384,           HH,   HH};
    for (int i=0;i<3;i++) ps.t[4+i]  = {igW  + (size_t)i*2*HH*HH, gateP + i*131072,          2*HH, HH};
    for (int i=0;i<3;i++) ps.t[7+i]  = {stW  + (size_t)i*2*HH*HH, gateP + i*131072 + 32768,  2*HH, HH};
    for (int i=0;i<3;i++) ps.t[10+i] = {fgW  + (size_t)i*2*HH*HH, gateP + i*131072 + 65536,  2*HH, HH};
    for (int i=0;i<3;i++) ps.t[13+i] = {ogW  + (size_t)i*2*HH*HH, gateP + i*131072 + 98304,  2*HH, HH};
    ps.t[16] = {outW, outP, HH, OUT_D};
    pack_k<<<dim3(128,17), 256, 0, stream>>>(ps);

    // ---- bucketized CSR build ----
    hipMemsetAsync(bcnt, 0, 128*4, stream);
    const int gE = (EE + 4095) / 4096;   // 196
    binh_k <<<gE, 256, 0, stream>>>(dst, bcnt);
    bscan_k<<<1, 128, 0, stream>>>(bcnt, bbase, gcur);
    binsc_k<<<gE, 256, 0, stream>>>(dst, src, gcur, staged);
    build_k<<<NBK, BK, 0, stream>>>(bcnt, bbase, staged, rp, deg, srcs);

    const int gN = (NN + 63) / 64;   // 782
    const int gA = (NN + 3) / 4;     // 12500

    // ---- h0 = x @ wxW + wxb -> muB ----
    rgemm_k<EPI_BF,4,2,IN_D,float><<<gN, 256, 0, stream>>>(
        x, wxP, wxb, nullptr, muB, nullptr, nullptr, NN);

    // ---- GAT layers ----
    const u16* hin = muB;
    for (int i = 0; i < DEPTH; ++i) {
        rgemm_k<EPI_ZEL,4,2,HH,u16><<<gN, 256, 0, stream>>>(
            hin, gatP + i*16384, attl + i*HH, attr + i*HH, zB, el, er, NN);
        gat_k<<<gA, 256, 0, stream>>>(zB, el, er, srcs, rp, deg, gatb + i*HH, coll[i]);
        hin = coll[i];
    }

    // ---- depth: single fused kernel (c in registers, mu in LDS) ----
    depth_k<<<gN, 512, 0, stream>>>(coll0, coll1, coll2, muB, gateP,
                                    igb, stb, fgb, ogb, NN);

    // ---- out = relu(mu @ outW + outb) -> f32 ----
    rgemm_k<EPI_RELU,4,1,HH,u16><<<gN, 256, 0, stream>>>(
        muB, outP, outb, nullptr, (float*)d_out, nullptr, nullptr, NN);
}

// Round 11
// 309.730 us; speedup vs baseline: 2.4791x; 1.0362x over previous
//
#include <hip/hip_runtime.h>
#include <math.h>
#include <type_traits>

#define NN 50000
#define EE 800000
#define IN_D 256
#define HH 128
#define OUT_D 64
#define DEPTH 3
#define BK 512
#define NBK 98    // ceil(NN/BK)

typedef unsigned short u16;
typedef __bf16  bf16x8 __attribute__((ext_vector_type(8)));
typedef short   short8 __attribute__((ext_vector_type(8)));
typedef float   f32x4  __attribute__((ext_vector_type(4)));

__device__ __forceinline__ u16 f2b(float f){
    unsigned u = __float_as_uint(f);
    u += 0x7fff + ((u>>16)&1);            // round-to-nearest-even
    return (u16)(u>>16);
}
__device__ __forceinline__ float b2f(u16 h){ return __uint_as_float(((unsigned)h)<<16); }

#define LOG2E 1.4426950408889634f
#if __has_builtin(__builtin_amdgcn_exp2f)
__device__ __forceinline__ float fexp2(float x){ return __builtin_amdgcn_exp2f(x); }
#else
__device__ __forceinline__ float fexp2(float x){ return exp2f(x); }
#endif
#if __has_builtin(__builtin_amdgcn_rcpf)
__device__ __forceinline__ float frcp(float x){ return __builtin_amdgcn_rcpf(x); }
#else
__device__ __forceinline__ float frcp(float x){ return 1.f/x; }
#endif
__device__ __forceinline__ float sigm(float x){ return frcp(1.f + fexp2(-x*LOG2E)); }
__device__ __forceinline__ float ftanh(float x){
    float ax = fabsf(x);
    float u = fexp2(ax * (-2.f*LOG2E));
    float r = (1.f - u) * frcp(1.f + u);
    return copysignf(r, x);
}

// ================= A-resident register GEMM (h0 / zel) =================
enum { EPI_BF=0, EPI_RELU=1, EPI_ZEL=2 };

template<int EPI, int WAVES, int CT, int K, typename TA>
__global__ __launch_bounds__(WAVES*64, 4) void rgemm_k(
    const TA* __restrict__ A1,
    const u16* __restrict__ Bp,
    const float* __restrict__ b1, const float* __restrict__ b2,
    void* __restrict__ Out, float* __restrict__ aux1, float* __restrict__ aux2,
    int Nrows)
{
    constexpr int TH = WAVES*64;
    constexpr int KS = K/32;
    constexpr int M  = WAVES*CT*16;
    __shared__ u16 As[64*K];
    __shared__ float elp[(EPI==EPI_ZEL)?64*WAVES:1];
    __shared__ float erp[(EPI==EPI_ZEL)?64*WAVES:1];

    const int tid = threadIdx.x;
    const int rb  = blockIdx.x*64;

    constexpr int CHUNKS = 64*K/(TH*8);
    #pragma unroll
    for (int c = 0; c < CHUNKS; ++c) {
        int h = (tid + c*TH)*8;
        int row = h / K, kk = h % K;
        int grow = rb + row; if (grow >= Nrows) grow = Nrows-1;
        short8 v;
        if constexpr (std::is_same<TA,float>::value) {
            const float* p = (const float*)A1 + (size_t)grow*K + kk;
            float4 x0 = *(const float4*)p;
            float4 x1 = *(const float4*)(p+4);
            v[0]=(short)f2b(x0.x); v[1]=(short)f2b(x0.y); v[2]=(short)f2b(x0.z); v[3]=(short)f2b(x0.w);
            v[4]=(short)f2b(x1.x); v[5]=(short)f2b(x1.y); v[6]=(short)f2b(x1.z); v[7]=(short)f2b(x1.w);
        } else {
            v = *(const short8*)((const u16*)A1 + (size_t)grow*K + kk);
        }
        int byte = row*(K*2) + ((kk*2) ^ ((row&7)<<4));
        *(short8*)((char*)As + byte) = v;
    }
    __syncthreads();

    const int lane = tid & 63, w = tid >> 6;
    const int ml = lane & 15, ksel = lane >> 4;
    f32x4 acc[4][CT] = {};
    #pragma unroll
    for (int ks = 0; ks < KS; ++ks) {
        bf16x8 a[4];
        #pragma unroll
        for (int rt = 0; rt < 4; ++rt) {
            int row = rt*16 + ml;
            int byte = row*(K*2) + (((ks*32 + ksel*8)*2) ^ ((row&7)<<4));
            a[rt] = *(const bf16x8*)((const char*)As + byte);
        }
        #pragma unroll
        for (int j = 0; j < CT; ++j) {
            int ctg = j*WAVES + w;
            bf16x8 b = *(const bf16x8*)(Bp + (((size_t)(ctg*KS + ks))<<9) + lane*8);
            #pragma unroll
            for (int rt = 0; rt < 4; ++rt)
                acc[rt][j] = __builtin_amdgcn_mfma_f32_16x16x32_bf16(a[rt], b, acc[rt][j], 0,0,0);
        }
    }

    if constexpr (EPI==EPI_BF || EPI==EPI_RELU) {
        #pragma unroll
        for (int rt = 0; rt < 4; ++rt)
        #pragma unroll
        for (int r = 0; r < 4; ++r) {
            int row = rb + rt*16 + ksel*4 + r;
            if (row >= Nrows) continue;
            #pragma unroll
            for (int j = 0; j < CT; ++j) {
                int gc = (j*WAVES + w)*16 + ml;
                float vv = acc[rt][j][r] + b1[gc];
                if (EPI==EPI_BF) ((u16*)Out)[(size_t)row*M + gc]   = f2b(vv);
                else             ((float*)Out)[(size_t)row*M + gc] = fmaxf(vv, 0.f);
            }
        }
    } else {   // EPI_ZEL
        float pel[4][4] = {}, per[4][4] = {};
        #pragma unroll
        for (int j = 0; j < CT; ++j) {
            int gc = (j*WAVES + w)*16 + ml;
            float alc = b1[gc], arc = b2[gc];
            #pragma unroll
            for (int rt = 0; rt < 4; ++rt)
            #pragma unroll
            for (int r = 0; r < 4; ++r) {
                int row = rb + rt*16 + ksel*4 + r;
                float vv = acc[rt][j][r];
                if (row < Nrows) ((u16*)Out)[(size_t)row*HH + gc] = f2b(vv);
                pel[rt][r] = fmaf(vv, alc, pel[rt][r]);
                per[rt][r] = fmaf(vv, arc, per[rt][r]);
            }
        }
        #pragma unroll
        for (int msk = 1; msk < 16; msk <<= 1)
            #pragma unroll
            for (int rt = 0; rt < 4; ++rt)
            #pragma unroll
            for (int r = 0; r < 4; ++r) {
                pel[rt][r] += __shfl_xor(pel[rt][r], msk);
                per[rt][r] += __shfl_xor(per[rt][r], msk);
            }
        if (ml == 0) {
            #pragma unroll
            for (int rt = 0; rt < 4; ++rt)
            #pragma unroll
            for (int r = 0; r < 4; ++r) {
                int lr = rt*16 + ksel*4 + r;
                elp[lr*WAVES + w] = pel[rt][r];
                erp[lr*WAVES + w] = per[rt][r];
            }
        }
        __syncthreads();
        if (tid < 64) {
            int row = rb + tid;
            if (row < Nrows) {
                float s1 = 0.f, s2 = 0.f;
                #pragma unroll
                for (int wv = 0; wv < WAVES; ++wv) { s1 += elp[tid*WAVES+wv]; s2 += erp[tid*WAVES+wv]; }
                aux1[row] = s1; aux2[row] = s2;
            }
        }
    }
}

// ================= fused 3-layer depth kernel + out GEMM =================
// Block owns 64 rows for the whole depth phase. mu lives in a swizzled LDS tile,
// c in registers (wave-local cols). Each layer runs TWO k-passes (ig,st then
// fg,og) to halve accumulator pressure (R10 spilled: acc[4][4]+cc+arch > 128
// regs -> 59MB scratch writes). Layer loop fully unrolled (no runtime-indexed
// pointer array -> no scratch, rule #20). Tail: waves 0-3 compute
// relu(mu @ outW + outb) straight from the Ms tile -> d_out (saves the separate
// out dispatch + 25.6MB mu round-trip).
__global__ __launch_bounds__(512, 3) void depth_k(
    const u16* __restrict__ coll0, const u16* __restrict__ coll1, const u16* __restrict__ coll2,
    const u16* __restrict__ mu0,
    const u16* __restrict__ gateP, const u16* __restrict__ outP,
    const float* __restrict__ igb, const float* __restrict__ stb,
    const float* __restrict__ fgb, const float* __restrict__ ogb,
    const float* __restrict__ outb, float* __restrict__ Out,
    int Nrows)
{
    __shared__ u16 As[64*HH];   // coll tile (swizzled), 16KB
    __shared__ u16 Ms[64*HH];   // mu tile  (swizzled), 16KB
    const int tid = threadIdx.x;
    const int rb  = blockIdx.x*64;
    const int lane = tid & 63, w = tid >> 6;
    const int ml = lane & 15, ksel = lane >> 4;
    const int gcg = w*16 + ml;

    // stage initial mu (= h0)
    #pragma unroll
    for (int c = 0; c < 2; ++c) {
        int h = (tid + c*512)*8;
        int row = h >> 7, kk = h & 127;
        int grow = rb + row; if (grow >= Nrows) grow = Nrows-1;
        short8 v = *(const short8*)(mu0 + (size_t)grow*HH + kk);
        *(short8*)((char*)Ms + row*256 + ((kk*2) ^ ((row&7)<<4))) = v;
    }

    float cc[4][4];
    #pragma unroll
    for (int i = 0; i < DEPTH; ++i) {
        const u16* coll = (i==0) ? coll0 : (i==1) ? coll1 : coll2;
        __syncthreads();   // prior layer's As/Ms k-loop reads complete
        #pragma unroll
        for (int c = 0; c < 2; ++c) {
            int h = (tid + c*512)*8;
            int row = h >> 7, kk = h & 127;
            int grow = rb + row; if (grow >= Nrows) grow = Nrows-1;
            short8 v = *(const short8*)(coll + (size_t)grow*HH + kk);
            *(short8*)((char*)As + row*256 + ((kk*2) ^ ((row&7)<<4))) = v;
        }
        __syncthreads();   // As ready; prev Ms writes visible

        float P_[4][4];
        {   // ---- pass A: ig, st ----
            f32x4 acc[4][2] = {};
            #pragma unroll
            for (int ks = 0; ks < 8; ++ks) {
                const char* Sb = (ks < 4) ? (const char*)As : (const char*)Ms;
                int kk2 = ((ks & 3)*32 + ksel*8)*2;
                bf16x8 a[4];
                #pragma unroll
                for (int rt = 0; rt < 4; ++rt) {
                    int row = rt*16 + ml;
                    a[rt] = *(const bf16x8*)(Sb + row*256 + (kk2 ^ ((row&7)<<4)));
                }
                #pragma unroll
                for (int g = 0; g < 2; ++g) {
                    bf16x8 b = *(const bf16x8*)(gateP + (size_t)i*131072 + (g*8 + w)*4096 + ks*512 + lane*8);
                    #pragma unroll
                    for (int rt = 0; rt < 4; ++rt)
                        acc[rt][g] = __builtin_amdgcn_mfma_f32_16x16x32_bf16(a[rt], b, acc[rt][g], 0,0,0);
                }
            }
            float bi = igb[i*HH + gcg], bs = stb[i*HH + gcg];
            #pragma unroll
            for (int rt = 0; rt < 4; ++rt)
            #pragma unroll
            for (int r = 0; r < 4; ++r)
                P_[rt][r] = sigm(acc[rt][0][r] + bi) * ftanh(acc[rt][1][r] + bs);
        }
        {   // ---- pass B: fg, og ----
            f32x4 acc[4][2] = {};
            #pragma unroll
            for (int ks = 0; ks < 8; ++ks) {
                const char* Sb = (ks < 4) ? (const char*)As : (const char*)Ms;
                int kk2 = ((ks & 3)*32 + ksel*8)*2;
                bf16x8 a[4];
                #pragma unroll
                for (int rt = 0; rt < 4; ++rt) {
                    int row = rt*16 + ml;
                    a[rt] = *(const bf16x8*)(Sb + row*256 + (kk2 ^ ((row&7)<<4)));
                }
                #pragma unroll
                for (int g = 0; g < 2; ++g) {
                    bf16x8 b = *(const bf16x8*)(gateP + (size_t)i*131072 + ((g+2)*8 + w)*4096 + ks*512 + lane*8);
                    #pragma unroll
                    for (int rt = 0; rt < 4; ++rt)
                        acc[rt][g] = __builtin_amdgcn_mfma_f32_16x16x32_bf16(a[rt], b, acc[rt][g], 0,0,0);
                }
            }
            float bf_ = fgb[i*HH + gcg], bo = ogb[i*HH + gcg];
            __syncthreads();   // ALL waves' Ms reads (both passes) done before overwrite
            #pragma unroll
            for (int rt = 0; rt < 4; ++rt)
            #pragma unroll
            for (int r = 0; r < 4; ++r) {
                float fg = sigm(acc[rt][0][r] + bf_);
                float og = sigm(acc[rt][1][r] + bo);
                float cn = (i == 0) ? P_[rt][r] : fmaf(fg, cc[rt][r], P_[rt][r]);
                cc[rt][r] = cn;
                float mun = og * ftanh(cn);
                int lrow = rt*16 + ksel*4 + r;
                *(u16*)((char*)Ms + lrow*256 + ((gcg*2) ^ ((lrow&7)<<4))) = f2b(mun);
            }
        }
    }
    __syncthreads();   // final mu visible in Ms

    // ---- fused out GEMM: relu(mu @ outW + outb) -> d_out (waves 0-3) ----
    if (w < 4) {
        f32x4 acc[4] = {};
        #pragma unroll
        for (int ks = 0; ks < 4; ++ks) {
            int kk2 = (ks*32 + ksel*8)*2;
            bf16x8 a[4];
            #pragma unroll
            for (int rt = 0; rt < 4; ++rt) {
                int row = rt*16 + ml;
                a[rt] = *(const bf16x8*)((const char*)Ms + row*256 + (kk2 ^ ((row&7)<<4)));
            }
            bf16x8 b = *(const bf16x8*)(outP + (size_t)((w*4 + ks)<<9) + lane*8);
            #pragma unroll
            for (int rt = 0; rt < 4; ++rt)
                acc[rt] = __builtin_amdgcn_mfma_f32_16x16x32_bf16(a[rt], b, acc[rt], 0,0,0);
        }
        int gc = w*16 + ml;
        float bb = outb[gc];
        #pragma unroll
        for (int rt = 0; rt < 4; ++rt)
        #pragma unroll
        for (int r = 0; r < 4; ++r) {
            int row = rb + rt*16 + ksel*4 + r;
            if (row < Nrows)
                Out[(size_t)row*OUT_D + gc] = fmaxf(acc[rt][r] + bb, 0.f);
        }
    }
}

// ================= weight pack =================
struct PK  { const float* s; u16* d; int K; int Mc; };
struct PKs { PK t[17]; };
__global__ __launch_bounds__(256) void pack_k(PKs ps){
    const PK t = ps.t[blockIdx.y];
    int o = blockIdx.x*256 + threadIdx.x;
    if (o >= t.K * t.Mc) return;
    int i = o & 7, lane = (o>>3) & 63, rst = o >> 9;
    int KS = t.K >> 5;
    int ks = rst % KS, ct = rst / KS;
    int col = ct*16 + (lane & 15);
    int k   = ks*32 + (lane>>4)*8 + i;
    t.d[o] = f2b(t.s[(size_t)k*t.Mc + col]);
}

// ================= bucketized CSR build =================
__global__ __launch_bounds__(256) void binh_k(const int* __restrict__ dst, int* __restrict__ bcnt){
    __shared__ int h[NBK];
    int t = threadIdx.x;
    if (t < NBK) h[t] = 0;
    __syncthreads();
    int base = blockIdx.x*4096;
    #pragma unroll
    for (int c = 0; c < 16; ++c){ int e = base + c*256 + t; if (e < EE) atomicAdd(&h[dst[e]>>9], 1); }
    __syncthreads();
    if (t < NBK && h[t]) atomicAdd(&bcnt[t], h[t]);
}
__global__ __launch_bounds__(128) void bscan_k(const int* __restrict__ bcnt,
                                               int* __restrict__ bbase, int* __restrict__ gcur){
    __shared__ int s[128];
    int t = threadIdx.x;
    int v = (t < NBK) ? bcnt[t] : 0;
    s[t] = v; __syncthreads();
    for (int off=1; off<128; off<<=1){ int x = (t>=off)? s[t-off] : 0; __syncthreads(); s[t] += x; __syncthreads(); }
    if (t < NBK){ bbase[t] = s[t]-v; gcur[t] = s[t]-v; }
}
__global__ __launch_bounds__(256) void binsc_k(const int* __restrict__ dst, const int* __restrict__ src,
                                               int* __restrict__ gcur, unsigned* __restrict__ staged){
    __shared__ int h[NBK], bb[NBK], lc[NBK];
    int t = threadIdx.x;
    if (t < NBK){ h[t]=0; lc[t]=0; }
    __syncthreads();
    int base = blockIdx.x*4096;
    int d[16], s[16];
    #pragma unroll
    for (int c = 0; c < 16; ++c){
        int e = base + c*256 + t; d[c] = -1;
        if (e < EE){ d[c] = dst[e]; s[c] = src[e]; atomicAdd(&h[d[c]>>9], 1); }
    }
    __syncthreads();
    if (t < NBK && h[t]) bb[t] = atomicAdd(&gcur[t], h[t]);
    __syncthreads();
    #pragma unroll
    for (int c = 0; c < 16; ++c) if (d[c] >= 0){
        int b = d[c]>>9;
        int r = atomicAdd(&lc[b], 1);
        staged[bb[b] + r] = ((unsigned)(d[c] & 511) << 16) | (unsigned)s[c];
    }
}
__global__ __launch_bounds__(BK) void build_k(const int* __restrict__ bcnt, const int* __restrict__ bbase,
                                              const unsigned* __restrict__ staged,
                                              int* __restrict__ rp, int* __restrict__ deg, u16* __restrict__ srcs){
    __shared__ int soff[BK], cur[BK];
    int t = threadIdx.x, bk = blockIdx.x;
    int n0 = bk*BK;
    soff[t] = 0; cur[t] = 0;
    __syncthreads();
    int cb = bcnt[bk], eb = bbase[bk];
    for (int j = t; j < cb; j += BK) atomicAdd(&soff[staged[eb+j]>>16], 1);
    __syncthreads();
    int d0 = soff[t];
    for (int off=1; off<BK; off<<=1){ int x = (t>=off)? soff[t-off] : 0; __syncthreads(); soff[t] += x; __syncthreads(); }
    int ex = soff[t] - d0;
    __syncthreads();
    soff[t] = ex;
    int n = n0 + t;
    if (n < NN){ deg[n] = d0; rp[n] = eb + ex; }
    __syncthreads();
    for (int j = t; j < cb; j += BK){
        unsigned p = staged[eb+j];
        int l = p >> 16;
        int r = atomicAdd(&cur[l], 1);
        srcs[eb + soff[l] + r] = (u16)(p & 0xffff);
    }
}

// ================= fused attention-softmax + gather =================
// Wave-uniform gather trip count: all lanes execute the same iterations so every
// __shfl source lane is active (R8 lesson). OOB slots: weight 0, gather z[0].
__global__ __launch_bounds__(256) void gat_k(
    const u16* __restrict__ z, const float* __restrict__ el, const float* __restrict__ er,
    const u16* __restrict__ srcs, const int* __restrict__ rp, const int* __restrict__ deg,
    const float* __restrict__ bias, u16* __restrict__ hout)
{
    int n = blockIdx.x*4 + (threadIdx.x>>6);
    if (n >= NN) return;
    int lane = threadIdx.x & 63;
    int start = rp[n], cnt = deg[n];
    float ern = er[n];
    const int slot = lane >> 4;
    const int ch   = (lane & 15) * 8;
    float acc[8] = {};

    if (cnt <= 64) {
        float v = -1e30f; int s_reg = 0;
        if (lane < cnt) {
            s_reg = srcs[start + lane];
            float tv = el[s_reg] + ern;
            v = tv >= 0.f ? tv : 0.2f*tv;
        }
        float m = v;
        #pragma unroll
        for (int off=1; off<64; off<<=1) m = fmaxf(m, __shfl_xor(m, off));
        float a = (lane < cnt) ? fexp2((v - m)*LOG2E) : 0.f;
        float ss = a;
        #pragma unroll
        for (int off=1; off<64; off<<=1) ss += __shfl_xor(ss, off);
        float a_reg = a * frcp(fmaxf(ss, 1e-16f));

        const int cntp = (cnt + 7) & ~7;
        for (int i = slot; i < cntp; i += 8) {
            float w0 = __shfl(a_reg, i),   w1 = __shfl(a_reg, i+4);
            int   s0 = __shfl(s_reg, i),   s1 = __shfl(s_reg, i+4);
            short8 v0 = *(const short8*)(z + (size_t)s0*HH + ch);
            short8 v1 = *(const short8*)(z + (size_t)s1*HH + ch);
            #pragma unroll
            for (int j=0;j<8;j++) acc[j] = fmaf(w1, b2f((u16)v1[j]), fmaf(w0, b2f((u16)v0[j]), acc[j]));
        }
    } else {
        float m = -1e30f;
        for (int i=lane; i<cnt; i+=64){ float tv = el[srcs[start+i]] + ern; tv = tv>=0.f?tv:0.2f*tv; m = fmaxf(m, tv); }
        #pragma unroll
        for (int off=1; off<64; off<<=1) m = fmaxf(m, __shfl_xor(m, off));
        float ss = 0.f;
        for (int i=lane; i<cnt; i+=64){ float tv = el[srcs[start+i]] + ern; tv = tv>=0.f?tv:0.2f*tv; ss += fexp2((tv-m)*LOG2E); }
        #pragma unroll
        for (int off=1; off<64; off<<=1) ss += __shfl_xor(ss, off);
        float inv = frcp(fmaxf(ss, 1e-16f));
        for (int i=slot; i<cnt; i+=4) {
            int sn = srcs[start+i];
            float tv = el[sn] + ern; tv = tv>=0.f?tv:0.2f*tv;
            float w0 = fexp2((tv-m)*LOG2E) * inv;
            short8 v0 = *(const short8*)(z + (size_t)sn*HH + ch);
            #pragma unroll
            for (int j=0;j<8;j++) acc[j] = fmaf(w0, b2f((u16)v0[j]), acc[j]);
        }
    }
    #pragma unroll
    for (int j=0;j<8;j++){ acc[j] += __shfl_xor(acc[j],16); acc[j] += __shfl_xor(acc[j],32); }
    if (slot == 0) {
        short8 o8;
        #pragma unroll
        for (int j=0;j<8;j++) o8[j] = (short)f2b(ftanh(acc[j] + bias[ch+j]));
        *(short8*)(hout + (size_t)n*HH + ch) = o8;
    }
}

extern "C" void kernel_launch(void* const* d_in, const int* in_sizes, int n_in,
                              void* d_out, int out_size, void* d_ws, size_t ws_size,
                              hipStream_t stream)
{
    const float* x    = (const float*)d_in[0];
    const int*   src  = (const int*)d_in[1];
    const int*   dst  = (const int*)d_in[2];
    const float* wxW  = (const float*)d_in[3];
    const float* wxb  = (const float*)d_in[4];
    const float* gatW = (const float*)d_in[5];
    const float* gatb = (const float*)d_in[6];
    const float* attl = (const float*)d_in[7];
    const float* attr = (const float*)d_in[8];
    const float* igW  = (const float*)d_in[9];
    const float* igb  = (const float*)d_in[10];
    const float* fgW  = (const float*)d_in[11];
    const float* fgb  = (const float*)d_in[12];
    const float* ogW  = (const float*)d_in[13];
    const float* ogb  = (const float*)d_in[14];
    const float* stW  = (const float*)d_in[15];
    const float* stb  = (const float*)d_in[16];
    const float* outW = (const float*)d_in[17];
    const float* outb = (const float*)d_in[18];

    char* w = (char*)d_ws;
    auto alloc = [&](size_t bytes)->char* { char* p = w; w += (bytes + 255) & ~(size_t)255; return p; };
    const size_t NH = (size_t)NN * HH;
    u16*      muB    = (u16*)alloc(NH*2);
    u16*      zB     = (u16*)alloc(NH*2);
    u16*      coll0  = (u16*)alloc(NH*2);
    u16*      coll1  = (u16*)alloc(NH*2);
    u16*      coll2  = (u16*)alloc(NH*2);
    float*    el     = (float*)alloc((size_t)NN*4);
    float*    er     = (float*)alloc((size_t)NN*4);
    unsigned* staged = (unsigned*)alloc((size_t)EE*4);
    u16*      srcs   = (u16*)alloc((size_t)EE*2);
    int*      deg    = (int*)alloc((size_t)NN*4);
    int*      rp     = (int*)alloc((size_t)NN*4);
    int*      bcnt   = (int*)alloc(128*4);
    int*      bbase  = (int*)alloc(128*4);
    int*      gcur   = (int*)alloc(128*4);
    u16*      bpool  = (u16*)alloc(483328*2);
    u16* wxP   = bpool;
    u16* gatP  = bpool + 32768;
    u16* gateP = bpool + 81920;
    u16* outP  = bpool + 475136;
    u16* coll[3] = {coll0, coll1, coll2};

    // ---- pack weights into MFMA fragment order ----
    PKs ps;
    ps.t[0] = {wxW, wxP, IN_D, HH};
    for (int i=0;i<3;i++) ps.t[1+i]  = {gatW + (size_t)i*HH*HH,   gatP  + i*16384,           HH,   HH};
    for (int i=0;i<3;i++) ps.t[4+i]  = {igW  + (size_t)i*2*HH*HH, gateP + i*131072,          2*HH, HH};
    for (int i=0;i<3;i++) ps.t[7+i]  = {stW  + (size_t)i*2*HH*HH, gateP + i*131072 + 32768,  2*HH, HH};
    for (int i=0;i<3;i++) ps.t[10+i] = {fgW  + (size_t)i*2*HH*HH, gateP + i*131072 + 65536,  2*HH, HH};
    for (int i=0;i<3;i++) ps.t[13+i] = {ogW  + (size_t)i*2*HH*HH, gateP + i*131072 + 98304,  2*HH, HH};
    ps.t[16] = {outW, outP, HH, OUT_D};
    pack_k<<<dim3(128,17), 256, 0, stream>>>(ps);

    // ---- bucketized CSR build ----
    hipMemsetAsync(bcnt, 0, 128*4, stream);
    const int gE = (EE + 4095) / 4096;   // 196
    binh_k <<<gE, 256, 0, stream>>>(dst, bcnt);
    bscan_k<<<1, 128, 0, stream>>>(bcnt, bbase, gcur);
    binsc_k<<<gE, 256, 0, stream>>>(dst, src, gcur, staged);
    build_k<<<NBK, BK, 0, stream>>>(bcnt, bbase, staged, rp, deg, srcs);

    const int gN = (NN + 63) / 64;   // 782
    const int gA = (NN + 3) / 4;     // 12500

    // ---- h0 = x @ wxW + wxb -> muB ----
    rgemm_k<EPI_BF,4,2,IN_D,float><<<gN, 256, 0, stream>>>(
        x, wxP, wxb, nullptr, muB, nullptr, nullptr, NN);

    // ---- GAT layers ----
    const u16* hin = muB;
    for (int i = 0; i < DEPTH; ++i) {
        rgemm_k<EPI_ZEL,4,2,HH,u16><<<gN, 256, 0, stream>>>(
            hin, gatP + i*16384, attl + i*HH, attr + i*HH, zB, el, er, NN);
        gat_k<<<gA, 256, 0, stream>>>(zB, el, er, srcs, rp, deg, gatb + i*HH, coll[i]);
        hin = coll[i];
    }

    // ---- depth + out: single fused kernel ----
    depth_k<<<gN, 512, 0, stream>>>(coll0, coll1, coll2, muB, gateP, outP,
                                    igb, stb, fgb, ogb, outb, (float*)d_out, NN);
}

// Round 12
// 305.186 us; speedup vs baseline: 2.5160x; 1.0149x over previous
//
#include <hip/hip_runtime.h>
#include <math.h>
#include <type_traits>

#define NN 50000
#define EE 800000
#define IN_D 256
#define HH 128
#define OUT_D 64
#define DEPTH 3
#define BK 512
#define NBK 98    // ceil(NN/BK)

typedef unsigned short u16;
typedef __bf16  bf16x8 __attribute__((ext_vector_type(8)));
typedef short   short8 __attribute__((ext_vector_type(8)));
typedef float   f32x4  __attribute__((ext_vector_type(4)));

__device__ __forceinline__ u16 f2b(float f){
    unsigned u = __float_as_uint(f);
    u += 0x7fff + ((u>>16)&1);            // round-to-nearest-even
    return (u16)(u>>16);
}
__device__ __forceinline__ float b2f(u16 h){ return __uint_as_float(((unsigned)h)<<16); }

#define LOG2E 1.4426950408889634f
#if __has_builtin(__builtin_amdgcn_exp2f)
__device__ __forceinline__ float fexp2(float x){ return __builtin_amdgcn_exp2f(x); }
#else
__device__ __forceinline__ float fexp2(float x){ return exp2f(x); }
#endif
#if __has_builtin(__builtin_amdgcn_rcpf)
__device__ __forceinline__ float frcp(float x){ return __builtin_amdgcn_rcpf(x); }
#else
__device__ __forceinline__ float frcp(float x){ return 1.f/x; }
#endif
__device__ __forceinline__ float sigm(float x){ return frcp(1.f + fexp2(-x*LOG2E)); }
__device__ __forceinline__ float ftanh(float x){
    float ax = fabsf(x);
    float u = fexp2(ax * (-2.f*LOG2E));
    float r = (1.f - u) * frcp(1.f + u);
    return copysignf(r, x);
}

// ================= A-resident register GEMM (h0 / zel) =================
enum { EPI_BF=0, EPI_RELU=1, EPI_ZEL=2 };

template<int EPI, int WAVES, int CT, int K, typename TA>
__global__ __launch_bounds__(WAVES*64, 4) void rgemm_k(
    const TA* __restrict__ A1,
    const u16* __restrict__ Bp,
    const float* __restrict__ b1, const float* __restrict__ b2,
    void* __restrict__ Out, float* __restrict__ aux1, float* __restrict__ aux2,
    int Nrows)
{
    constexpr int TH = WAVES*64;
    constexpr int KS = K/32;
    constexpr int M  = WAVES*CT*16;
    __shared__ u16 As[64*K];
    __shared__ float elp[(EPI==EPI_ZEL)?64*WAVES:1];
    __shared__ float erp[(EPI==EPI_ZEL)?64*WAVES:1];

    const int tid = threadIdx.x;
    const int rb  = blockIdx.x*64;

    constexpr int CHUNKS = 64*K/(TH*8);
    #pragma unroll
    for (int c = 0; c < CHUNKS; ++c) {
        int h = (tid + c*TH)*8;
        int row = h / K, kk = h % K;
        int grow = rb + row; if (grow >= Nrows) grow = Nrows-1;
        short8 v;
        if constexpr (std::is_same<TA,float>::value) {
            const float* p = (const float*)A1 + (size_t)grow*K + kk;
            float4 x0 = *(const float4*)p;
            float4 x1 = *(const float4*)(p+4);
            v[0]=(short)f2b(x0.x); v[1]=(short)f2b(x0.y); v[2]=(short)f2b(x0.z); v[3]=(short)f2b(x0.w);
            v[4]=(short)f2b(x1.x); v[5]=(short)f2b(x1.y); v[6]=(short)f2b(x1.z); v[7]=(short)f2b(x1.w);
        } else {
            v = *(const short8*)((const u16*)A1 + (size_t)grow*K + kk);
        }
        int byte = row*(K*2) + ((kk*2) ^ ((row&7)<<4));
        *(short8*)((char*)As + byte) = v;
    }
    __syncthreads();

    const int lane = tid & 63, w = tid >> 6;
    const int ml = lane & 15, ksel = lane >> 4;
    f32x4 acc[4][CT] = {};
    #pragma unroll
    for (int ks = 0; ks < KS; ++ks) {
        bf16x8 a[4];
        #pragma unroll
        for (int rt = 0; rt < 4; ++rt) {
            int row = rt*16 + ml;
            int byte = row*(K*2) + (((ks*32 + ksel*8)*2) ^ ((row&7)<<4));
            a[rt] = *(const bf16x8*)((const char*)As + byte);
        }
        #pragma unroll
        for (int j = 0; j < CT; ++j) {
            int ctg = j*WAVES + w;
            bf16x8 b = *(const bf16x8*)(Bp + (((size_t)(ctg*KS + ks))<<9) + lane*8);
            #pragma unroll
            for (int rt = 0; rt < 4; ++rt)
                acc[rt][j] = __builtin_amdgcn_mfma_f32_16x16x32_bf16(a[rt], b, acc[rt][j], 0,0,0);
        }
    }

    if constexpr (EPI==EPI_BF || EPI==EPI_RELU) {
        #pragma unroll
        for (int rt = 0; rt < 4; ++rt)
        #pragma unroll
        for (int r = 0; r < 4; ++r) {
            int row = rb + rt*16 + ksel*4 + r;
            if (row >= Nrows) continue;
            #pragma unroll
            for (int j = 0; j < CT; ++j) {
                int gc = (j*WAVES + w)*16 + ml;
                float vv = acc[rt][j][r] + b1[gc];
                if (EPI==EPI_BF) ((u16*)Out)[(size_t)row*M + gc]   = f2b(vv);
                else             ((float*)Out)[(size_t)row*M + gc] = fmaxf(vv, 0.f);
            }
        }
    } else {   // EPI_ZEL
        float pel[4][4] = {}, per[4][4] = {};
        #pragma unroll
        for (int j = 0; j < CT; ++j) {
            int gc = (j*WAVES + w)*16 + ml;
            float alc = b1[gc], arc = b2[gc];
            #pragma unroll
            for (int rt = 0; rt < 4; ++rt)
            #pragma unroll
            for (int r = 0; r < 4; ++r) {
                int row = rb + rt*16 + ksel*4 + r;
                float vv = acc[rt][j][r];
                if (row < Nrows) ((u16*)Out)[(size_t)row*HH + gc] = f2b(vv);
                pel[rt][r] = fmaf(vv, alc, pel[rt][r]);
                per[rt][r] = fmaf(vv, arc, per[rt][r]);
            }
        }
        #pragma unroll
        for (int msk = 1; msk < 16; msk <<= 1)
            #pragma unroll
            for (int rt = 0; rt < 4; ++rt)
            #pragma unroll
            for (int r = 0; r < 4; ++r) {
                pel[rt][r] += __shfl_xor(pel[rt][r], msk);
                per[rt][r] += __shfl_xor(per[rt][r], msk);
            }
        if (ml == 0) {
            #pragma unroll
            for (int rt = 0; rt < 4; ++rt)
            #pragma unroll
            for (int r = 0; r < 4; ++r) {
                int lr = rt*16 + ksel*4 + r;
                elp[lr*WAVES + w] = pel[rt][r];
                erp[lr*WAVES + w] = per[rt][r];
            }
        }
        __syncthreads();
        if (tid < 64) {
            int row = rb + tid;
            if (row < Nrows) {
                float s1 = 0.f, s2 = 0.f;
                #pragma unroll
                for (int wv = 0; wv < WAVES; ++wv) { s1 += elp[tid*WAVES+wv]; s2 += erp[tid*WAVES+wv]; }
                aux1[row] = s1; aux2[row] = s2;
            }
        }
    }
}

// ================= fused 3-layer depth kernel + out GEMM =================
// Block owns 64 rows. mu in swizzled LDS tile, c in registers (wave-local cols).
// Single k-pass per layer (acc[4][4]; fits under the 170-reg cap of bounds(512,3)
// -- R10's spill was the 128-cap + runtime-indexed pointer array).
// T14 prefetch: layer i+1's coll global loads are issued right after layer i's
// As write and land during the k-loop; only layer 0's load latency is exposed.
// Tail: all 8 waves compute relu(mu @ outW + outb) from the Ms tile -> d_out.
__global__ __launch_bounds__(512, 3) void depth_k(
    const u16* __restrict__ coll0, const u16* __restrict__ coll1, const u16* __restrict__ coll2,
    const u16* __restrict__ mu0,
    const u16* __restrict__ gateP, const u16* __restrict__ outP,
    const float* __restrict__ igb, const float* __restrict__ stb,
    const float* __restrict__ fgb, const float* __restrict__ ogb,
    const float* __restrict__ outb, float* __restrict__ Out,
    int Nrows)
{
    __shared__ u16 As[64*HH];   // coll tile (swizzled), 16KB
    __shared__ u16 Ms[64*HH];   // mu tile  (swizzled), 16KB
    const int tid = threadIdx.x;
    const int rb  = blockIdx.x*64;
    const int lane = tid & 63, w = tid >> 6;
    const int ml = lane & 15, ksel = lane >> 4;
    const int gcg = w*16 + ml;

    // this thread's two staging chunks (fixed for all tiles)
    const int h0_ = tid*8,        h1_ = (tid+512)*8;
    const int row0 = h0_ >> 7,    kk0 = h0_ & 127;
    const int row1 = h1_ >> 7,    kk1 = h1_ & 127;
    int gr0 = rb + row0; if (gr0 >= Nrows) gr0 = Nrows-1;
    int gr1 = rb + row1; if (gr1 >= Nrows) gr1 = Nrows-1;
    const size_t off0 = (size_t)gr0*HH + kk0, off1 = (size_t)gr1*HH + kk1;
    const int dst0 = row0*256 + ((kk0*2) ^ ((row0&7)<<4));
    const int dst1 = row1*256 + ((kk1*2) ^ ((row1&7)<<4));

    // stage initial mu (= h0) and prefetch coll0
    *(short8*)((char*)Ms + dst0) = *(const short8*)(mu0 + off0);
    *(short8*)((char*)Ms + dst1) = *(const short8*)(mu0 + off1);
    short8 pf0 = *(const short8*)(coll0 + off0);
    short8 pf1 = *(const short8*)(coll0 + off1);

    float cc[4][4];
    #pragma unroll
    for (int i = 0; i < DEPTH; ++i) {
        __syncthreads();   // prev k-loop's As reads complete (no-op at i=0)
        *(short8*)((char*)As + dst0) = pf0;
        *(short8*)((char*)As + dst1) = pf1;
        if (i == 0) { pf0 = *(const short8*)(coll1 + off0); pf1 = *(const short8*)(coll1 + off1); }
        if (i == 1) { pf0 = *(const short8*)(coll2 + off0); pf1 = *(const short8*)(coll2 + off1); }
        __syncthreads();   // As ready; prev Ms writes (and initial Ms) visible

        f32x4 acc[4][4] = {};   // [rt][gate]
        #pragma unroll
        for (int ks = 0; ks < 8; ++ks) {
            const char* Sb = (ks < 4) ? (const char*)As : (const char*)Ms;
            int kk2 = ((ks & 3)*32 + ksel*8)*2;
            bf16x8 a[4];
            #pragma unroll
            for (int rt = 0; rt < 4; ++rt) {
                int row = rt*16 + ml;
                a[rt] = *(const bf16x8*)(Sb + row*256 + (kk2 ^ ((row&7)<<4)));
            }
            #pragma unroll
            for (int g = 0; g < 4; ++g) {
                bf16x8 b = *(const bf16x8*)(gateP + (size_t)i*131072 + (g*8 + w)*4096 + ks*512 + lane*8);
                #pragma unroll
                for (int rt = 0; rt < 4; ++rt)
                    acc[rt][g] = __builtin_amdgcn_mfma_f32_16x16x32_bf16(a[rt], b, acc[rt][g], 0,0,0);
            }
        }
        __syncthreads();   // ALL waves' Ms reads done before overwrite

        float bi = igb[i*HH + gcg], bs = stb[i*HH + gcg];
        float bf_ = fgb[i*HH + gcg], bo = ogb[i*HH + gcg];
        #pragma unroll
        for (int rt = 0; rt < 4; ++rt)
        #pragma unroll
        for (int r = 0; r < 4; ++r) {
            float ig = sigm (acc[rt][0][r] + bi);
            float st = ftanh(acc[rt][1][r] + bs);
            float fg = sigm (acc[rt][2][r] + bf_);
            float og = sigm (acc[rt][3][r] + bo);
            float P  = ig * st;
            float cn = (i == 0) ? P : fmaf(fg, cc[rt][r], P);
            cc[rt][r] = cn;
            float mun = og * ftanh(cn);
            int lrow = rt*16 + ksel*4 + r;
            *(u16*)((char*)Ms + lrow*256 + ((gcg*2) ^ ((lrow&7)<<4))) = f2b(mun);
        }
    }
    __syncthreads();   // final mu visible in Ms

    // ---- fused out GEMM: relu(mu @ outW + outb) -> d_out (all 8 waves) ----
    {
        const int ct = w & 3;          // col tile (OUT_D = 4 x 16)
        const int rh = (w >> 2) * 2;   // row-tile base: waves 0-3 rows 0-31, 4-7 rows 32-63
        f32x4 acc[2] = {};
        #pragma unroll
        for (int ks = 0; ks < 4; ++ks) {
            int kk2 = (ks*32 + ksel*8)*2;
            bf16x8 a[2];
            #pragma unroll
            for (int q = 0; q < 2; ++q) {
                int row = (rh + q)*16 + ml;
                a[q] = *(const bf16x8*)((const char*)Ms + row*256 + (kk2 ^ ((row&7)<<4)));
            }
            bf16x8 b = *(const bf16x8*)(outP + (size_t)((ct*4 + ks)<<9) + lane*8);
            #pragma unroll
            for (int q = 0; q < 2; ++q)
                acc[q] = __builtin_amdgcn_mfma_f32_16x16x32_bf16(a[q], b, acc[q], 0,0,0);
        }
        int gc = ct*16 + ml;
        float bb = outb[gc];
        #pragma unroll
        for (int q = 0; q < 2; ++q)
        #pragma unroll
        for (int r = 0; r < 4; ++r) {
            int row = rb + (rh + q)*16 + ksel*4 + r;
            if (row < Nrows)
                Out[(size_t)row*OUT_D + gc] = fmaxf(acc[q][r] + bb, 0.f);
        }
    }
}

// ================= weight pack =================
struct PK  { const float* s; u16* d; int K; int Mc; };
struct PKs { PK t[17]; };
__global__ __launch_bounds__(256) void pack_k(PKs ps){
    const PK t = ps.t[blockIdx.y];
    int o = blockIdx.x*256 + threadIdx.x;
    if (o >= t.K * t.Mc) return;
    int i = o & 7, lane = (o>>3) & 63, rst = o >> 9;
    int KS = t.K >> 5;
    int ks = rst % KS, ct = rst / KS;
    int col = ct*16 + (lane & 15);
    int k   = ks*32 + (lane>>4)*8 + i;
    t.d[o] = f2b(t.s[(size_t)k*t.Mc + col]);
}

// ================= bucketized CSR build =================
__global__ __launch_bounds__(256) void binh_k(const int* __restrict__ dst, int* __restrict__ bcnt){
    __shared__ int h[NBK];
    int t = threadIdx.x;
    if (t < NBK) h[t] = 0;
    __syncthreads();
    int base = blockIdx.x*4096;
    #pragma unroll
    for (int c = 0; c < 16; ++c){ int e = base + c*256 + t; if (e < EE) atomicAdd(&h[dst[e]>>9], 1); }
    __syncthreads();
    if (t < NBK && h[t]) atomicAdd(&bcnt[t], h[t]);
}
__global__ __launch_bounds__(128) void bscan_k(const int* __restrict__ bcnt,
                                               int* __restrict__ bbase, int* __restrict__ gcur){
    __shared__ int s[128];
    int t = threadIdx.x;
    int v = (t < NBK) ? bcnt[t] : 0;
    s[t] = v; __syncthreads();
    for (int off=1; off<128; off<<=1){ int x = (t>=off)? s[t-off] : 0; __syncthreads(); s[t] += x; __syncthreads(); }
    if (t < NBK){ bbase[t] = s[t]-v; gcur[t] = s[t]-v; }
}
__global__ __launch_bounds__(256) void binsc_k(const int* __restrict__ dst, const int* __restrict__ src,
                                               int* __restrict__ gcur, unsigned* __restrict__ staged){
    __shared__ int h[NBK], bb[NBK], lc[NBK];
    int t = threadIdx.x;
    if (t < NBK){ h[t]=0; lc[t]=0; }
    __syncthreads();
    int base = blockIdx.x*4096;
    int d[16], s[16];
    #pragma unroll
    for (int c = 0; c < 16; ++c){
        int e = base + c*256 + t; d[c] = -1;
        if (e < EE){ d[c] = dst[e]; s[c] = src[e]; atomicAdd(&h[d[c]>>9], 1); }
    }
    __syncthreads();
    if (t < NBK && h[t]) bb[t] = atomicAdd(&gcur[t], h[t]);
    __syncthreads();
    #pragma unroll
    for (int c = 0; c < 16; ++c) if (d[c] >= 0){
        int b = d[c]>>9;
        int r = atomicAdd(&lc[b], 1);
        staged[bb[b] + r] = ((unsigned)(d[c] & 511) << 16) | (unsigned)s[c];
    }
}
__global__ __launch_bounds__(BK) void build_k(const int* __restrict__ bcnt, const int* __restrict__ bbase,
                                              const unsigned* __restrict__ staged,
                                              int* __restrict__ rp, int* __restrict__ deg, u16* __restrict__ srcs){
    __shared__ int soff[BK], cur[BK];
    int t = threadIdx.x, bk = blockIdx.x;
    int n0 = bk*BK;
    soff[t] = 0; cur[t] = 0;
    __syncthreads();
    int cb = bcnt[bk], eb = bbase[bk];
    for (int j = t; j < cb; j += BK) atomicAdd(&soff[staged[eb+j]>>16], 1);
    __syncthreads();
    int d0 = soff[t];
    for (int off=1; off<BK; off<<=1){ int x = (t>=off)? soff[t-off] : 0; __syncthreads(); soff[t] += x; __syncthreads(); }
    int ex = soff[t] - d0;
    __syncthreads();
    soff[t] = ex;
    int n = n0 + t;
    if (n < NN){ deg[n] = d0; rp[n] = eb + ex; }
    __syncthreads();
    for (int j = t; j < cb; j += BK){
        unsigned p = staged[eb+j];
        int l = p >> 16;
        int r = atomicAdd(&cur[l], 1);
        srcs[eb + soff[l] + r] = (u16)(p & 0xffff);
    }
}

// ================= fused attention-softmax + gather =================
// Wave-uniform gather trip count: all lanes execute the same iterations so every
// __shfl source lane is active (R8 lesson). OOB slots: weight 0, gather z[0].
__global__ __launch_bounds__(256) void gat_k(
    const u16* __restrict__ z, const float* __restrict__ el, const float* __restrict__ er,
    const u16* __restrict__ srcs, const int* __restrict__ rp, const int* __restrict__ deg,
    const float* __restrict__ bias, u16* __restrict__ hout)
{
    int n = blockIdx.x*4 + (threadIdx.x>>6);
    if (n >= NN) return;
    int lane = threadIdx.x & 63;
    int start = rp[n], cnt = deg[n];
    float ern = er[n];
    const int slot = lane >> 4;
    const int ch   = (lane & 15) * 8;
    float acc[8] = {};

    if (cnt <= 64) {
        float v = -1e30f; int s_reg = 0;
        if (lane < cnt) {
            s_reg = srcs[start + lane];
            float tv = el[s_reg] + ern;
            v = tv >= 0.f ? tv : 0.2f*tv;
        }
        float m = v;
        #pragma unroll
        for (int off=1; off<64; off<<=1) m = fmaxf(m, __shfl_xor(m, off));
        float a = (lane < cnt) ? fexp2((v - m)*LOG2E) : 0.f;
        float ss = a;
        #pragma unroll
        for (int off=1; off<64; off<<=1) ss += __shfl_xor(ss, off);
        float a_reg = a * frcp(fmaxf(ss, 1e-16f));

        const int cntp = (cnt + 7) & ~7;
        for (int i = slot; i < cntp; i += 8) {
            float w0 = __shfl(a_reg, i),   w1 = __shfl(a_reg, i+4);
            int   s0 = __shfl(s_reg, i),   s1 = __shfl(s_reg, i+4);
            short8 v0 = *(const short8*)(z + (size_t)s0*HH + ch);
            short8 v1 = *(const short8*)(z + (size_t)s1*HH + ch);
            #pragma unroll
            for (int j=0;j<8;j++) acc[j] = fmaf(w1, b2f((u16)v1[j]), fmaf(w0, b2f((u16)v0[j]), acc[j]));
        }
    } else {
        float m = -1e30f;
        for (int i=lane; i<cnt; i+=64){ float tv = el[srcs[start+i]] + ern; tv = tv>=0.f?tv:0.2f*tv; m = fmaxf(m, tv); }
        #pragma unroll
        for (int off=1; off<64; off<<=1) m = fmaxf(m, __shfl_xor(m, off));
        float ss = 0.f;
        for (int i=lane; i<cnt; i+=64){ float tv = el[srcs[start+i]] + ern; tv = tv>=0.f?tv:0.2f*tv; ss += fexp2((tv-m)*LOG2E); }
        #pragma unroll
        for (int off=1; off<64; off<<=1) ss += __shfl_xor(ss, off);
        float inv = frcp(fmaxf(ss, 1e-16f));
        for (int i=slot; i<cnt; i+=4) {
            int sn = srcs[start+i];
            float tv = el[sn] + ern; tv = tv>=0.f?tv:0.2f*tv;
            float w0 = fexp2((tv-m)*LOG2E) * inv;
            short8 v0 = *(const short8*)(z + (size_t)sn*HH + ch);
            #pragma unroll
            for (int j=0;j<8;j++) acc[j] = fmaf(w0, b2f((u16)v0[j]), acc[j]);
        }
    }
    #pragma unroll
    for (int j=0;j<8;j++){ acc[j] += __shfl_xor(acc[j],16); acc[j] += __shfl_xor(acc[j],32); }
    if (slot == 0) {
        short8 o8;
        #pragma unroll
        for (int j=0;j<8;j++) o8[j] = (short)f2b(ftanh(acc[j] + bias[ch+j]));
        *(short8*)(hout + (size_t)n*HH + ch) = o8;
    }
}

extern "C" void kernel_launch(void* const* d_in, const int* in_sizes, int n_in,
                              void* d_out, int out_size, void* d_ws, size_t ws_size,
                              hipStream_t stream)
{
    const float* x    = (const float*)d_in[0];
    const int*   src  = (const int*)d_in[1];
    const int*   dst  = (const int*)d_in[2];
    const float* wxW  = (const float*)d_in[3];
    const float* wxb  = (const float*)d_in[4];
    const float* gatW = (const float*)d_in[5];
    const float* gatb = (const float*)d_in[6];
    const float* attl = (const float*)d_in[7];
    const float* attr = (const float*)d_in[8];
    const float* igW  = (const float*)d_in[9];
    const float* igb  = (const float*)d_in[10];
    const float* fgW  = (const float*)d_in[11];
    const float* fgb  = (const float*)d_in[12];
    const float* ogW  = (const float*)d_in[13];
    const float* ogb  = (const float*)d_in[14];
    const float* stW  = (const float*)d_in[15];
    const float* stb  = (const float*)d_in[16];
    const float* outW = (const float*)d_in[17];
    const float* outb = (const float*)d_in[18];

    char* w = (char*)d_ws;
    auto alloc = [&](size_t bytes)->char* { char* p = w; w += (bytes + 255) & ~(size_t)255; return p; };
    const size_t NH = (size_t)NN * HH;
    u16*      muB    = (u16*)alloc(NH*2);
    u16*      zB     = (u16*)alloc(NH*2);
    u16*      coll0  = (u16*)alloc(NH*2);
    u16*      coll1  = (u16*)alloc(NH*2);
    u16*      coll2  = (u16*)alloc(NH*2);
    float*    el     = (float*)alloc((size_t)NN*4);
    float*    er     = (float*)alloc((size_t)NN*4);
    unsigned* staged = (unsigned*)alloc((size_t)EE*4);
    u16*      srcs   = (u16*)alloc((size_t)EE*2);
    int*      deg    = (int*)alloc((size_t)NN*4);
    int*      rp     = (int*)alloc((size_t)NN*4);
    int*      bcnt   = (int*)alloc(128*4);
    int*      bbase  = (int*)alloc(128*4);
    int*      gcur   = (int*)alloc(128*4);
    u16*      bpool  = (u16*)alloc(483328*2);
    u16* wxP   = bpool;
    u16* gatP  = bpool + 32768;
    u16* gateP = bpool + 81920;
    u16* outP  = bpool + 475136;
    u16* coll[3] = {coll0, coll1, coll2};

    // ---- pack weights into MFMA fragment order ----
    PKs ps;
    ps.t[0] = {wxW, wxP, IN_D, HH};
    for (int i=0;i<3;i++) ps.t[1+i]  = {gatW + (size_t)i*HH*HH,   gatP  + i*16384,           HH,   HH};
    for (int i=0;i<3;i++) ps.t[4+i]  = {igW  + (size_t)i*2*HH*HH, gateP + i*131072,          2*HH, HH};
    for (int i=0;i<3;i++) ps.t[7+i]  = {stW  + (size_t)i*2*HH*HH, gateP + i*131072 + 32768,  2*HH, HH};
    for (int i=0;i<3;i++) ps.t[10+i] = {fgW  + (size_t)i*2*HH*HH, gateP + i*131072 + 65536,  2*HH, HH};
    for (int i=0;i<3;i++) ps.t[13+i] = {ogW  + (size_t)i*2*HH*HH, gateP + i*131072 + 98304,  2*HH, HH};
    ps.t[16] = {outW, outP, HH, OUT_D};
    pack_k<<<dim3(128,17), 256, 0, stream>>>(ps);

    // ---- bucketized CSR build ----
    hipMemsetAsync(bcnt, 0, 128*4, stream);
    const int gE = (EE + 4095) / 4096;   // 196
    binh_k <<<gE, 256, 0, stream>>>(dst, bcnt);
    bscan_k<<<1, 128, 0, stream>>>(bcnt, bbase, gcur);
    binsc_k<<<gE, 256, 0, stream>>>(dst, src, gcur, staged);
    build_k<<<NBK, BK, 0, stream>>>(bcnt, bbase, staged, rp, deg, srcs);

    const int gN = (NN + 63) / 64;   // 782
    const int gA = (NN + 3) / 4;     // 12500

    // ---- h0 = x @ wxW + wxb -> muB ----
    rgemm_k<EPI_BF,4,2,IN_D,float><<<gN, 256, 0, stream>>>(
        x, wxP, wxb, nullptr, muB, nullptr, nullptr, NN);

    // ---- GAT layers ----
    const u16* hin = muB;
    for (int i = 0; i < DEPTH; ++i) {
        rgemm_k<EPI_ZEL,4,2,HH,u16><<<gN, 256, 0, stream>>>(
            hin, gatP + i*16384, attl + i*HH, attr + i*HH, zB, el, er, NN);
        gat_k<<<gA, 256, 0, stream>>>(zB, el, er, srcs, rp, deg, gatb + i*HH, coll[i]);
        hin = coll[i];
    }

    // ---- depth + out: single fused kernel ----
    depth_k<<<gN, 512, 0, stream>>>(coll0, coll1, coll2, muB, gateP, outP,
                                    igb, stb, fgb, ogb, outb, (float*)d_out, NN);
}

// Round 13
// 304.885 us; speedup vs baseline: 2.5185x; 1.0010x over previous
//
#include <hip/hip_runtime.h>
#include <math.h>
#include <type_traits>

#define NN 50000
#define EE 800000
#define IN_D 256
#define HH 128
#define OUT_D 64
#define DEPTH 3
#define BK 512
#define NBK 98    // ceil(NN/BK)

typedef unsigned short u16;
typedef __bf16  bf16x8 __attribute__((ext_vector_type(8)));
typedef short   short8 __attribute__((ext_vector_type(8)));
typedef float   f32x4  __attribute__((ext_vector_type(4)));

__device__ __forceinline__ u16 f2b(float f){
    unsigned u = __float_as_uint(f);
    u += 0x7fff + ((u>>16)&1);            // round-to-nearest-even
    return (u16)(u>>16);
}
__device__ __forceinline__ float b2f(u16 h){ return __uint_as_float(((unsigned)h)<<16); }

#define LOG2E 1.4426950408889634f
#if __has_builtin(__builtin_amdgcn_exp2f)
__device__ __forceinline__ float fexp2(float x){ return __builtin_amdgcn_exp2f(x); }
#else
__device__ __forceinline__ float fexp2(float x){ return exp2f(x); }
#endif
#if __has_builtin(__builtin_amdgcn_rcpf)
__device__ __forceinline__ float frcp(float x){ return __builtin_amdgcn_rcpf(x); }
#else
__device__ __forceinline__ float frcp(float x){ return 1.f/x; }
#endif
__device__ __forceinline__ float sigm(float x){ return frcp(1.f + fexp2(-x*LOG2E)); }
__device__ __forceinline__ float ftanh(float x){
    float ax = fabsf(x);
    float u = fexp2(ax * (-2.f*LOG2E));
    float r = (1.f - u) * frcp(1.f + u);
    return copysignf(r, x);
}

// ================= A-resident register GEMM (h0 / zel) =================
// LDS tile in MFMA-FRAGMENT order: frag(rt,ks) = 1KB, element slot = ksel*16+ml.
// k-loop reads are contiguous 1KB per wave (base + lane*16): conflict-free.
// Staging is row-minor (row = cidx&63): write banks 2-way (free).
enum { EPI_BF=0, EPI_RELU=1, EPI_ZEL=2 };

template<int EPI, int WAVES, int CT, int K, typename TA>
__global__ __launch_bounds__(WAVES*64, 4) void rgemm_k(
    const TA* __restrict__ A1,
    const u16* __restrict__ Bp,
    const float* __restrict__ b1, const float* __restrict__ b2,
    void* __restrict__ Out, float* __restrict__ aux1, float* __restrict__ aux2,
    int Nrows)
{
    constexpr int TH = WAVES*64;
    constexpr int KS = K/32;
    constexpr int M  = WAVES*CT*16;
    __shared__ u16 As[64*K];
    __shared__ float elp[(EPI==EPI_ZEL)?64*WAVES:1];
    __shared__ float erp[(EPI==EPI_ZEL)?64*WAVES:1];

    const int tid = threadIdx.x;
    const int rb  = blockIdx.x*64;

    constexpr int CHUNKS = 64*K/(TH*8);
    #pragma unroll
    for (int c = 0; c < CHUNKS; ++c) {
        int cidx = tid + c*TH;
        int row = cidx & 63, kseg = cidx >> 6;
        int grow = rb + row; if (grow >= Nrows) grow = Nrows-1;
        short8 v;
        if constexpr (std::is_same<TA,float>::value) {
            const float* p = (const float*)A1 + (size_t)grow*K + kseg*8;
            float4 x0 = *(const float4*)p;
            float4 x1 = *(const float4*)(p+4);
            v[0]=(short)f2b(x0.x); v[1]=(short)f2b(x0.y); v[2]=(short)f2b(x0.z); v[3]=(short)f2b(x0.w);
            v[4]=(short)f2b(x1.x); v[5]=(short)f2b(x1.y); v[6]=(short)f2b(x1.z); v[7]=(short)f2b(x1.w);
        } else {
            v = *(const short8*)((const u16*)A1 + (size_t)grow*K + kseg*8);
        }
        int byte = ((row>>4)*KS + (kseg>>2))*1024 + ((kseg&3)*16 + (row&15))*16;
        *(short8*)((char*)As + byte) = v;
    }
    __syncthreads();

    const int lane = tid & 63, w = tid >> 6;
    const int ml = lane & 15, ksel = lane >> 4;
    f32x4 acc[4][CT] = {};
    #pragma unroll
    for (int ks = 0; ks < KS; ++ks) {
        bf16x8 a[4];
        #pragma unroll
        for (int rt = 0; rt < 4; ++rt)
            a[rt] = *(const bf16x8*)((const char*)As + (rt*KS + ks)*1024 + lane*16);
        #pragma unroll
        for (int j = 0; j < CT; ++j) {
            int ctg = j*WAVES + w;
            bf16x8 b = *(const bf16x8*)(Bp + (((size_t)(ctg*KS + ks))<<9) + lane*8);
            #pragma unroll
            for (int rt = 0; rt < 4; ++rt)
                acc[rt][j] = __builtin_amdgcn_mfma_f32_16x16x32_bf16(a[rt], b, acc[rt][j], 0,0,0);
        }
    }

    if constexpr (EPI==EPI_BF || EPI==EPI_RELU) {
        #pragma unroll
        for (int rt = 0; rt < 4; ++rt)
        #pragma unroll
        for (int r = 0; r < 4; ++r) {
            int row = rb + rt*16 + ksel*4 + r;
            if (row >= Nrows) continue;
            #pragma unroll
            for (int j = 0; j < CT; ++j) {
                int gc = (j*WAVES + w)*16 + ml;
                float vv = acc[rt][j][r] + b1[gc];
                if (EPI==EPI_BF) ((u16*)Out)[(size_t)row*M + gc]   = f2b(vv);
                else             ((float*)Out)[(size_t)row*M + gc] = fmaxf(vv, 0.f);
            }
        }
    } else {   // EPI_ZEL
        float pel[4][4] = {}, per[4][4] = {};
        #pragma unroll
        for (int j = 0; j < CT; ++j) {
            int gc = (j*WAVES + w)*16 + ml;
            float alc = b1[gc], arc = b2[gc];
            #pragma unroll
            for (int rt = 0; rt < 4; ++rt)
            #pragma unroll
            for (int r = 0; r < 4; ++r) {
                int row = rb + rt*16 + ksel*4 + r;
                float vv = acc[rt][j][r];
                if (row < Nrows) ((u16*)Out)[(size_t)row*HH + gc] = f2b(vv);
                pel[rt][r] = fmaf(vv, alc, pel[rt][r]);
                per[rt][r] = fmaf(vv, arc, per[rt][r]);
            }
        }
        #pragma unroll
        for (int msk = 1; msk < 16; msk <<= 1)
            #pragma unroll
            for (int rt = 0; rt < 4; ++rt)
            #pragma unroll
            for (int r = 0; r < 4; ++r) {
                pel[rt][r] += __shfl_xor(pel[rt][r], msk);
                per[rt][r] += __shfl_xor(per[rt][r], msk);
            }
        if (ml == 0) {
            #pragma unroll
            for (int rt = 0; rt < 4; ++rt)
            #pragma unroll
            for (int r = 0; r < 4; ++r) {
                int lr = rt*16 + ksel*4 + r;
                elp[lr*WAVES + w] = pel[rt][r];
                erp[lr*WAVES + w] = per[rt][r];
            }
        }
        __syncthreads();
        if (tid < 64) {
            int row = rb + tid;
            if (row < Nrows) {
                float s1 = 0.f, s2 = 0.f;
                #pragma unroll
                for (int wv = 0; wv < WAVES; ++wv) { s1 += elp[tid*WAVES+wv]; s2 += erp[tid*WAVES+wv]; }
                aux1[row] = s1; aux2[row] = s2;
            }
        }
    }
}

// ================= fused 3-layer depth kernel + out GEMM =================
// Fragment-order LDS for As (coll) and Ms (mu): k-loop ds_reads are contiguous
// 1KB/wave (conflict-free; the R12 swizzle was 8-way conflicted because the
// row-XOR collided with ksel in addr bits 4-6). Staging row-minor (banks 2-way).
// Explicit B double-buffer (bc/bn) hides L2 latency. c in registers, coll
// prefetched one layer ahead. Tail: all 8 waves run the out-GEMM from Ms.
__global__ __launch_bounds__(512, 3) void depth_k(
    const u16* __restrict__ coll0, const u16* __restrict__ coll1, const u16* __restrict__ coll2,
    const u16* __restrict__ mu0,
    const u16* __restrict__ gateP, const u16* __restrict__ outP,
    const float* __restrict__ igb, const float* __restrict__ stb,
    const float* __restrict__ fgb, const float* __restrict__ ogb,
    const float* __restrict__ outb, float* __restrict__ Out,
    int Nrows)
{
    __shared__ u16 As[64*HH];   // 16 frags x 1KB
    __shared__ u16 Ms[64*HH];
    const int tid = threadIdx.x;
    const int rb  = blockIdx.x*64;
    const int lane = tid & 63, w = tid >> 6;
    const int ml = lane & 15, ksel = lane >> 4;
    const int gcg = w*16 + ml;

    // staging chunks, row-minor: cidx -> row = cidx&63, kseg = cidx>>6 (0..15)
    const int c0 = tid, c1 = tid + 512;
    const int row0 = c0 & 63, kg0 = c0 >> 6;
    const int row1 = c1 & 63, kg1 = c1 >> 6;
    int gr0 = rb + row0; if (gr0 >= Nrows) gr0 = Nrows-1;
    int gr1 = rb + row1; if (gr1 >= Nrows) gr1 = Nrows-1;
    const size_t off0 = (size_t)gr0*HH + kg0*8, off1 = (size_t)gr1*HH + kg1*8;
    const int dst0 = ((row0>>4)*4 + (kg0>>2))*1024 + ((kg0&3)*16 + (row0&15))*16;
    const int dst1 = ((row1>>4)*4 + (kg1>>2))*1024 + ((kg1&3)*16 + (row1&15))*16;

    // stage initial mu (= h0) and prefetch coll0
    *(short8*)((char*)Ms + dst0) = *(const short8*)(mu0 + off0);
    *(short8*)((char*)Ms + dst1) = *(const short8*)(mu0 + off1);
    short8 pf0 = *(const short8*)(coll0 + off0);
    short8 pf1 = *(const short8*)(coll0 + off1);

    float cc[4][4];
    #pragma unroll
    for (int i = 0; i < DEPTH; ++i) {
        __syncthreads();   // prev k-loop's As reads complete (no-op at i=0)
        *(short8*)((char*)As + dst0) = pf0;
        *(short8*)((char*)As + dst1) = pf1;
        if (i == 0) { pf0 = *(const short8*)(coll1 + off0); pf1 = *(const short8*)(coll1 + off1); }
        if (i == 1) { pf0 = *(const short8*)(coll2 + off0); pf1 = *(const short8*)(coll2 + off1); }
        __syncthreads();   // As ready; prev Ms writes (and initial Ms) visible

        f32x4 acc[4][4] = {};   // [rt][gate]
        bf16x8 bc[4];
        #pragma unroll
        for (int g = 0; g < 4; ++g)
            bc[g] = *(const bf16x8*)(gateP + (size_t)i*131072 + (g*8 + w)*4096 + lane*8);
        #pragma unroll
        for (int ks = 0; ks < 8; ++ks) {
            bf16x8 bn[4];
            if (ks < 7) {
                #pragma unroll
                for (int g = 0; g < 4; ++g)
                    bn[g] = *(const bf16x8*)(gateP + (size_t)i*131072 + (g*8 + w)*4096 + (ks+1)*512 + lane*8);
            }
            const char* Sb = (ks < 4) ? (const char*)As : (const char*)Ms;
            bf16x8 a[4];
            #pragma unroll
            for (int rt = 0; rt < 4; ++rt)
                a[rt] = *(const bf16x8*)(Sb + (rt*4 + (ks&3))*1024 + lane*16);
            #pragma unroll
            for (int g = 0; g < 4; ++g)
                #pragma unroll
                for (int rt = 0; rt < 4; ++rt)
                    acc[rt][g] = __builtin_amdgcn_mfma_f32_16x16x32_bf16(a[rt], bc[g], acc[rt][g], 0,0,0);
            if (ks < 7) {
                #pragma unroll
                for (int g = 0; g < 4; ++g) bc[g] = bn[g];
            }
        }
        __syncthreads();   // ALL waves' Ms reads done before overwrite

        float bi = igb[i*HH + gcg], bs = stb[i*HH + gcg];
        float bf_ = fgb[i*HH + gcg], bo = ogb[i*HH + gcg];
        const int fks  = gcg >> 5;          // Ms frag column-group
        const int shi  = (gcg >> 3) & 3;    // slot high bits from column
        const int elem = gcg & 7;
        #pragma unroll
        for (int rt = 0; rt < 4; ++rt)
        #pragma unroll
        for (int r = 0; r < 4; ++r) {
            float ig = sigm (acc[rt][0][r] + bi);
            float st = ftanh(acc[rt][1][r] + bs);
            float fg = sigm (acc[rt][2][r] + bf_);
            float og = sigm (acc[rt][3][r] + bo);
            float P  = ig * st;
            float cn = (i == 0) ? P : fmaf(fg, cc[rt][r], P);
            cc[rt][r] = cn;
            float mun = og * ftanh(cn);
            int byte = (rt*4 + fks)*1024 + (shi*16 + (ksel*4 + r))*16 + elem*2;
            *(u16*)((char*)Ms + byte) = f2b(mun);
        }
    }
    __syncthreads();   // final mu visible in Ms

    // ---- fused out GEMM: relu(mu @ outW + outb) -> d_out (all 8 waves) ----
    {
        const int ct = w & 3;          // col tile (OUT_D = 4 x 16)
        const int rh = (w >> 2) * 2;   // row-tile base
        f32x4 acc[2] = {};
        #pragma unroll
        for (int ks = 0; ks < 4; ++ks) {
            bf16x8 a[2];
            #pragma unroll
            for (int q = 0; q < 2; ++q)
                a[q] = *(const bf16x8*)((const char*)Ms + ((rh+q)*4 + ks)*1024 + lane*16);
            bf16x8 b = *(const bf16x8*)(outP + (size_t)((ct*4 + ks)<<9) + lane*8);
            #pragma unroll
            for (int q = 0; q < 2; ++q)
                acc[q] = __builtin_amdgcn_mfma_f32_16x16x32_bf16(a[q], b, acc[q], 0,0,0);
        }
        int gc = ct*16 + ml;
        float bb = outb[gc];
        #pragma unroll
        for (int q = 0; q < 2; ++q)
        #pragma unroll
        for (int r = 0; r < 4; ++r) {
            int row = rb + (rh + q)*16 + ksel*4 + r;
            if (row < Nrows)
                Out[(size_t)row*OUT_D + gc] = fmaxf(acc[q][r] + bb, 0.f);
        }
    }
}

// ================= weight pack =================
struct PK  { const float* s; u16* d; int K; int Mc; };
struct PKs { PK t[17]; };
__global__ __launch_bounds__(256) void pack_k(PKs ps){
    const PK t = ps.t[blockIdx.y];
    int o = blockIdx.x*256 + threadIdx.x;
    if (o >= t.K * t.Mc) return;
    int i = o & 7, lane = (o>>3) & 63, rst = o >> 9;
    int KS = t.K >> 5;
    int ks = rst % KS, ct = rst / KS;
    int col = ct*16 + (lane & 15);
    int k   = ks*32 + (lane>>4)*8 + i;
    t.d[o] = f2b(t.s[(size_t)k*t.Mc + col]);
}

// ================= bucketized CSR build =================
__global__ __launch_bounds__(256) void binh_k(const int* __restrict__ dst, int* __restrict__ bcnt){
    __shared__ int h[NBK];
    int t = threadIdx.x;
    if (t < NBK) h[t] = 0;
    __syncthreads();
    int base = blockIdx.x*4096;
    #pragma unroll
    for (int c = 0; c < 16; ++c){ int e = base + c*256 + t; if (e < EE) atomicAdd(&h[dst[e]>>9], 1); }
    __syncthreads();
    if (t < NBK && h[t]) atomicAdd(&bcnt[t], h[t]);
}
__global__ __launch_bounds__(128) void bscan_k(const int* __restrict__ bcnt,
                                               int* __restrict__ bbase, int* __restrict__ gcur){
    __shared__ int s[128];
    int t = threadIdx.x;
    int v = (t < NBK) ? bcnt[t] : 0;
    s[t] = v; __syncthreads();
    for (int off=1; off<128; off<<=1){ int x = (t>=off)? s[t-off] : 0; __syncthreads(); s[t] += x; __syncthreads(); }
    if (t < NBK){ bbase[t] = s[t]-v; gcur[t] = s[t]-v; }
}
__global__ __launch_bounds__(256) void binsc_k(const int* __restrict__ dst, const int* __restrict__ src,
                                               int* __restrict__ gcur, unsigned* __restrict__ staged){
    __shared__ int h[NBK], bb[NBK], lc[NBK];
    int t = threadIdx.x;
    if (t < NBK){ h[t]=0; lc[t]=0; }
    __syncthreads();
    int base = blockIdx.x*4096;
    int d[16], s[16];
    #pragma unroll
    for (int c = 0; c < 16; ++c){
        int e = base + c*256 + t; d[c] = -1;
        if (e < EE){ d[c] = dst[e]; s[c] = src[e]; atomicAdd(&h[d[c]>>9], 1); }
    }
    __syncthreads();
    if (t < NBK && h[t]) bb[t] = atomicAdd(&gcur[t], h[t]);
    __syncthreads();
    #pragma unroll
    for (int c = 0; c < 16; ++c) if (d[c] >= 0){
        int b = d[c]>>9;
        int r = atomicAdd(&lc[b], 1);
        staged[bb[b] + r] = ((unsigned)(d[c] & 511) << 16) | (unsigned)s[c];
    }
}
__global__ __launch_bounds__(BK) void build_k(const int* __restrict__ bcnt, const int* __restrict__ bbase,
                                              const unsigned* __restrict__ staged,
                                              int* __restrict__ rp, int* __restrict__ deg, u16* __restrict__ srcs){
    __shared__ int soff[BK], cur[BK];
    int t = threadIdx.x, bk = blockIdx.x;
    int n0 = bk*BK;
    soff[t] = 0; cur[t] = 0;
    __syncthreads();
    int cb = bcnt[bk], eb = bbase[bk];
    for (int j = t; j < cb; j += BK) atomicAdd(&soff[staged[eb+j]>>16], 1);
    __syncthreads();
    int d0 = soff[t];
    for (int off=1; off<BK; off<<=1){ int x = (t>=off)? soff[t-off] : 0; __syncthreads(); soff[t] += x; __syncthreads(); }
    int ex = soff[t] - d0;
    __syncthreads();
    soff[t] = ex;
    int n = n0 + t;
    if (n < NN){ deg[n] = d0; rp[n] = eb + ex; }
    __syncthreads();
    for (int j = t; j < cb; j += BK){
        unsigned p = staged[eb+j];
        int l = p >> 16;
        int r = atomicAdd(&cur[l], 1);
        srcs[eb + soff[l] + r] = (u16)(p & 0xffff);
    }
}

// ================= fused attention-softmax + gather =================
// Wave-uniform gather trip count: all lanes execute the same iterations so every
// __shfl source lane is active (R8 lesson). OOB slots: weight 0, gather z[0].
__global__ __launch_bounds__(256) void gat_k(
    const u16* __restrict__ z, const float* __restrict__ el, const float* __restrict__ er,
    const u16* __restrict__ srcs, const int* __restrict__ rp, const int* __restrict__ deg,
    const float* __restrict__ bias, u16* __restrict__ hout)
{
    int n = blockIdx.x*4 + (threadIdx.x>>6);
    if (n >= NN) return;
    int lane = threadIdx.x & 63;
    int start = rp[n], cnt = deg[n];
    float ern = er[n];
    const int slot = lane >> 4;
    const int ch   = (lane & 15) * 8;
    float acc[8] = {};

    if (cnt <= 64) {
        float v = -1e30f; int s_reg = 0;
        if (lane < cnt) {
            s_reg = srcs[start + lane];
            float tv = el[s_reg] + ern;
            v = tv >= 0.f ? tv : 0.2f*tv;
        }
        float m = v;
        #pragma unroll
        for (int off=1; off<64; off<<=1) m = fmaxf(m, __shfl_xor(m, off));
        float a = (lane < cnt) ? fexp2((v - m)*LOG2E) : 0.f;
        float ss = a;
        #pragma unroll
        for (int off=1; off<64; off<<=1) ss += __shfl_xor(ss, off);
        float a_reg = a * frcp(fmaxf(ss, 1e-16f));

        const int cntp = (cnt + 7) & ~7;
        for (int i = slot; i < cntp; i += 8) {
            float w0 = __shfl(a_reg, i),   w1 = __shfl(a_reg, i+4);
            int   s0 = __shfl(s_reg, i),   s1 = __shfl(s_reg, i+4);
            short8 v0 = *(const short8*)(z + (size_t)s0*HH + ch);
            short8 v1 = *(const short8*)(z + (size_t)s1*HH + ch);
            #pragma unroll
            for (int j=0;j<8;j++) acc[j] = fmaf(w1, b2f((u16)v1[j]), fmaf(w0, b2f((u16)v0[j]), acc[j]));
        }
    } else {
        float m = -1e30f;
        for (int i=lane; i<cnt; i+=64){ float tv = el[srcs[start+i]] + ern; tv = tv>=0.f?tv:0.2f*tv; m = fmaxf(m, tv); }
        #pragma unroll
        for (int off=1; off<64; off<<=1) m = fmaxf(m, __shfl_xor(m, off));
        float ss = 0.f;
        for (int i=lane; i<cnt; i+=64){ float tv = el[srcs[start+i]] + ern; tv = tv>=0.f?tv:0.2f*tv; ss += fexp2((tv-m)*LOG2E); }
        #pragma unroll
        for (int off=1; off<64; off<<=1) ss += __shfl_xor(ss, off);
        float inv = frcp(fmaxf(ss, 1e-16f));
        for (int i=slot; i<cnt; i+=4) {
            int sn = srcs[start+i];
            float tv = el[sn] + ern; tv = tv>=0.f?tv:0.2f*tv;
            float w0 = fexp2((tv-m)*LOG2E) * inv;
            short8 v0 = *(const short8*)(z + (size_t)sn*HH + ch);
            #pragma unroll
            for (int j=0;j<8;j++) acc[j] = fmaf(w0, b2f((u16)v0[j]), acc[j]);
        }
    }
    #pragma unroll
    for (int j=0;j<8;j++){ acc[j] += __shfl_xor(acc[j],16); acc[j] += __shfl_xor(acc[j],32); }
    if (slot == 0) {
        short8 o8;
        #pragma unroll
        for (int j=0;j<8;j++) o8[j] = (short)f2b(ftanh(acc[j] + bias[ch+j]));
        *(short8*)(hout + (size_t)n*HH + ch) = o8;
    }
}

extern "C" void kernel_launch(void* const* d_in, const int* in_sizes, int n_in,
                              void* d_out, int out_size, void* d_ws, size_t ws_size,
                              hipStream_t stream)
{
    const float* x    = (const float*)d_in[0];
    const int*   src  = (const int*)d_in[1];
    const int*   dst  = (const int*)d_in[2];
    const float* wxW  = (const float*)d_in[3];
    const float* wxb  = (const float*)d_in[4];
    const float* gatW = (const float*)d_in[5];
    const float* gatb = (const float*)d_in[6];
    const float* attl = (const float*)d_in[7];
    const float* attr = (const float*)d_in[8];
    const float* igW  = (const float*)d_in[9];
    const float* igb  = (const float*)d_in[10];
    const float* fgW  = (const float*)d_in[11];
    const float* fgb  = (const float*)d_in[12];
    const float* ogW  = (const float*)d_in[13];
    const float* ogb  = (const float*)d_in[14];
    const float* stW  = (const float*)d_in[15];
    const float* stb  = (const float*)d_in[16];
    const float* outW = (const float*)d_in[17];
    const float* outb = (const float*)d_in[18];

    char* w = (char*)d_ws;
    auto alloc = [&](size_t bytes)->char* { char* p = w; w += (bytes + 255) & ~(size_t)255; return p; };
    const size_t NH = (size_t)NN * HH;
    u16*      muB    = (u16*)alloc(NH*2);
    u16*      zB     = (u16*)alloc(NH*2);
    u16*      coll0  = (u16*)alloc(NH*2);
    u16*      coll1  = (u16*)alloc(NH*2);
    u16*      coll2  = (u16*)alloc(NH*2);
    float*    el     = (float*)alloc((size_t)NN*4);
    float*    er     = (float*)alloc((size_t)NN*4);
    unsigned* staged = (unsigned*)alloc((size_t)EE*4);
    u16*      srcs   = (u16*)alloc((size_t)EE*2);
    int*      deg    = (int*)alloc((size_t)NN*4);
    int*      rp     = (int*)alloc((size_t)NN*4);
    int*      bcnt   = (int*)alloc(128*4);
    int*      bbase  = (int*)alloc(128*4);
    int*      gcur   = (int*)alloc(128*4);
    u16*      bpool  = (u16*)alloc(483328*2);
    u16* wxP   = bpool;
    u16* gatP  = bpool + 32768;
    u16* gateP = bpool + 81920;
    u16* outP  = bpool + 475136;
    u16* coll[3] = {coll0, coll1, coll2};

    // ---- pack weights into MFMA fragment order ----
    PKs ps;
    ps.t[0] = {wxW, wxP, IN_D, HH};
    for (int i=0;i<3;i++) ps.t[1+i]  = {gatW + (size_t)i*HH*HH,   gatP  + i*16384,           HH,   HH};
    for (int i=0;i<3;i++) ps.t[4+i]  = {igW  + (size_t)i*2*HH*HH, gateP + i*131072,          2*HH, HH};
    for (int i=0;i<3;i++) ps.t[7+i]  = {stW  + (size_t)i*2*HH*HH, gateP + i*131072 + 32768,  2*HH, HH};
    for (int i=0;i<3;i++) ps.t[10+i] = {fgW  + (size_t)i*2*HH*HH, gateP + i*131072 + 65536,  2*HH, HH};
    for (int i=0;i<3;i++) ps.t[13+i] = {ogW  + (size_t)i*2*HH*HH, gateP + i*131072 + 98304,  2*HH, HH};
    ps.t[16] = {outW, outP, HH, OUT_D};
    pack_k<<<dim3(128,17), 256, 0, stream>>>(ps);

    // ---- bucketized CSR build ----
    hipMemsetAsync(bcnt, 0, 128*4, stream);
    const int gE = (EE + 4095) / 4096;   // 196
    binh_k <<<gE, 256, 0, stream>>>(dst, bcnt);
    bscan_k<<<1, 128, 0, stream>>>(bcnt, bbase, gcur);
    binsc_k<<<gE, 256, 0, stream>>>(dst, src, gcur, staged);
    build_k<<<NBK, BK, 0, stream>>>(bcnt, bbase, staged, rp, deg, srcs);

    const int gN = (NN + 63) / 64;   // 782
    const int gA = (NN + 3) / 4;     // 12500

    // ---- h0 = x @ wxW + wxb -> muB ----
    rgemm_k<EPI_BF,4,2,IN_D,float><<<gN, 256, 0, stream>>>(
        x, wxP, wxb, nullptr, muB, nullptr, nullptr, NN);

    // ---- GAT layers ----
    const u16* hin = muB;
    for (int i = 0; i < DEPTH; ++i) {
        rgemm_k<EPI_ZEL,4,2,HH,u16><<<gN, 256, 0, stream>>>(
            hin, gatP + i*16384, attl + i*HH, attr + i*HH, zB, el, er, NN);
        gat_k<<<gA, 256, 0, stream>>>(zB, el, er, srcs, rp, deg, gatb + i*HH, coll[i]);
        hin = coll[i];
    }

    // ---- depth + out: single fused kernel ----
    depth_k<<<gN, 512, 0, stream>>>(coll0, coll1, coll2, muB, gateP, outP,
                                    igb, stb, fgb, ogb, outb, (float*)d_out, NN);
}